// Round 1
// baseline (3706.040 us; speedup 1.0000x reference)
//
#include <hip/hip_runtime.h>
#include <hip/hip_bf16.h>

#define NEG_SLOPE 0.2f

// ---------------- GEMM1: h1 = x @ W1  [n,512]x[512,64], fused att reductions ----------------
__global__ __launch_bounds__(256) void gemm1_att(
    const float* __restrict__ x, const float* __restrict__ W,
    const float* __restrict__ att_src, const float* __restrict__ att_dst,
    float* __restrict__ h1, float* __restrict__ asrc, float* __restrict__ adst, int n)
{
    __shared__ float As[64][65];   // [k][row], pad 65 to break bank conflicts
    __shared__ float Bs[64][64];   // [k][col]
    const int t  = threadIdx.x;
    const int rb = blockIdx.x * 64;
    const int ty = t >> 4;         // 0..15 -> row group
    const int tx = t & 15;         // 0..15 -> col group
    float acc[4][4] = {};

    for (int k0 = 0; k0 < 512; k0 += 64) {
        // stage A: rows rb..rb+63, k k0..k0+63 (transposed into As[k][r])
        #pragma unroll
        for (int rr = 0; rr < 4; ++rr) {
            int r = (t >> 4) + rr * 16;
            int c = (t & 15) * 4;
            float4 v = make_float4(0.f, 0.f, 0.f, 0.f);
            int gr = rb + r;
            if (gr < n) v = *(const float4*)(x + (size_t)gr * 512 + k0 + c);
            As[c + 0][r] = v.x; As[c + 1][r] = v.y; As[c + 2][r] = v.z; As[c + 3][r] = v.w;
        }
        // stage B: W[k0+kk][0..63]
        #pragma unroll
        for (int rr = 0; rr < 4; ++rr) {
            int kk = (t >> 4) + rr * 16;
            int c  = (t & 15) * 4;
            *(float4*)&Bs[kk][c] = *(const float4*)(W + (size_t)(k0 + kk) * 64 + c);
        }
        __syncthreads();
        #pragma unroll
        for (int kk = 0; kk < 64; ++kk) {
            float a0 = As[kk][ty * 4 + 0];
            float a1 = As[kk][ty * 4 + 1];
            float a2 = As[kk][ty * 4 + 2];
            float a3 = As[kk][ty * 4 + 3];
            float4 b = *(const float4*)&Bs[kk][tx * 4];
            acc[0][0] += a0 * b.x; acc[0][1] += a0 * b.y; acc[0][2] += a0 * b.z; acc[0][3] += a0 * b.w;
            acc[1][0] += a1 * b.x; acc[1][1] += a1 * b.y; acc[1][2] += a1 * b.z; acc[1][3] += a1 * b.w;
            acc[2][0] += a2 * b.x; acc[2][1] += a2 * b.y; acc[2][2] += a2 * b.z; acc[2][3] += a2 * b.w;
            acc[3][0] += a3 * b.x; acc[3][1] += a3 * b.y; acc[3][2] += a3 * b.z; acc[3][3] += a3 * b.w;
        }
        __syncthreads();
    }

    // epilogue: store h1, fused a_src/a_dst (head = 8 cols; this thread's 4 cols are one half)
    const int head = tx >> 1;
    const int halfoff = (tx & 1) * 4;
    #pragma unroll
    for (int i = 0; i < 4; ++i) {
        int gr = rb + ty * 4 + i;
        float ps = acc[i][0] * att_src[head * 8 + halfoff + 0]
                 + acc[i][1] * att_src[head * 8 + halfoff + 1]
                 + acc[i][2] * att_src[head * 8 + halfoff + 2]
                 + acc[i][3] * att_src[head * 8 + halfoff + 3];
        float pd = acc[i][0] * att_dst[head * 8 + halfoff + 0]
                 + acc[i][1] * att_dst[head * 8 + halfoff + 1]
                 + acc[i][2] * att_dst[head * 8 + halfoff + 2]
                 + acc[i][3] * att_dst[head * 8 + halfoff + 3];
        ps += __shfl_xor(ps, 1);
        pd += __shfl_xor(pd, 1);
        if (gr < n) {
            *(float4*)(h1 + (size_t)gr * 64 + tx * 4) = make_float4(acc[i][0], acc[i][1], acc[i][2], acc[i][3]);
            if ((tx & 1) == 0) {
                asrc[gr * 8 + head] = ps;
                adst[gr * 8 + head] = pd;
            }
        }
    }
}

// ---------------- edge pass layer 1: one thread per (edge, head) ----------------
__global__ __launch_bounds__(256) void edge1(
    const int* __restrict__ ei, const float* __restrict__ asrc, const float* __restrict__ adst,
    const float* __restrict__ h1, float* __restrict__ denom, float* __restrict__ acc,
    int E, int n)
{
    long long t = (long long)blockIdx.x * blockDim.x + threadIdx.x;
    long long total = (long long)(E + n) * 8;
    if (t >= total) return;
    int e = (int)(t >> 3);
    int h = (int)(t & 7);
    int s, d;
    if (e < E) { s = ei[e]; d = ei[E + e]; } else { s = d = e - E; }
    float av = asrc[s * 8 + h] + adst[d * 8 + h];
    av = av > 0.f ? av : NEG_SLOPE * av;
    float ex = __expf(av);
    unsafeAtomicAdd(denom + d * 8 + h, ex);
    const float4* hp = (const float4*)(h1 + (size_t)s * 64 + h * 8);
    float4 m0 = hp[0], m1 = hp[1];
    float* ap = acc + (size_t)d * 64 + h * 8;
    unsafeAtomicAdd(ap + 0, ex * m0.x);
    unsafeAtomicAdd(ap + 1, ex * m0.y);
    unsafeAtomicAdd(ap + 2, ex * m0.z);
    unsafeAtomicAdd(ap + 3, ex * m0.w);
    unsafeAtomicAdd(ap + 4, ex * m1.x);
    unsafeAtomicAdd(ap + 5, ex * m1.y);
    unsafeAtomicAdd(ap + 6, ex * m1.z);
    unsafeAtomicAdd(ap + 7, ex * m1.w);
}

// ---------------- finalize layer1: /denom + bias, ELU (in-place acc -> h2in) ----------------
__global__ __launch_bounds__(256) void finalize1(
    float* __restrict__ acc, const float* __restrict__ denom, const float* __restrict__ b1, int n)
{
    int idx = blockIdx.x * blockDim.x + threadIdx.x;
    if (idx >= n * 64) return;
    int nn = idx >> 6;
    int j  = idx & 63;
    float v = acc[idx] / (denom[nn * 8 + (j >> 3)] + 1e-16f) + b1[j];
    acc[idx] = v > 0.f ? v : (__expf(v) - 1.f);
}

// ---------------- GEMM2: h2 = h2in @ W2 [n,64]x[64,16], fused att2 ----------------
__global__ __launch_bounds__(256) void gemm2_att(
    const float* __restrict__ h2in, const float* __restrict__ W2,
    const float* __restrict__ att_src2, const float* __restrict__ att_dst2,
    float* __restrict__ h2, float* __restrict__ asrc2, float* __restrict__ adst2, int n)
{
    __shared__ float Ws[64][16];
    const int t = threadIdx.x;
    ((float4*)Ws)[t] = ((const float4*)W2)[t];   // 1024 floats
    __syncthreads();
    int node = blockIdx.x * 16 + (t >> 4);
    int j = t & 15;
    if (node >= n) return;
    float a = 0.f;
    #pragma unroll
    for (int k4 = 0; k4 < 16; ++k4) {
        float4 hv = *(const float4*)(h2in + (size_t)node * 64 + k4 * 4);
        a += hv.x * Ws[k4 * 4 + 0][j] + hv.y * Ws[k4 * 4 + 1][j]
           + hv.z * Ws[k4 * 4 + 2][j] + hv.w * Ws[k4 * 4 + 3][j];
    }
    h2[node * 16 + j] = a;
    float ps = a * att_src2[j];
    float pd = a * att_dst2[j];
    #pragma unroll
    for (int o = 8; o; o >>= 1) { ps += __shfl_xor(ps, o, 16); pd += __shfl_xor(pd, o, 16); }
    if (j == 0) { asrc2[node] = ps; adst2[node] = pd; }
}

// ---------------- edge pass layer 2: 4 threads per edge ----------------
__global__ __launch_bounds__(256) void edge2(
    const int* __restrict__ ei, const float* __restrict__ asrc2, const float* __restrict__ adst2,
    const float* __restrict__ h2, float* __restrict__ denom2, float* __restrict__ acc2,
    int E, int n)
{
    long long t = (long long)blockIdx.x * blockDim.x + threadIdx.x;
    long long total = (long long)(E + n) * 4;
    if (t >= total) return;
    int e = (int)(t >> 2);
    int q = (int)(t & 3);
    int s, d;
    if (e < E) { s = ei[e]; d = ei[E + e]; } else { s = d = e - E; }
    float av = asrc2[s] + adst2[d];
    av = av > 0.f ? av : NEG_SLOPE * av;
    float ex = __expf(av);
    if (q == 0) unsafeAtomicAdd(denom2 + d, ex);
    float4 hv = *(const float4*)(h2 + (size_t)s * 16 + q * 4);
    float* ap = acc2 + (size_t)d * 16 + q * 4;
    unsafeAtomicAdd(ap + 0, ex * hv.x);
    unsafeAtomicAdd(ap + 1, ex * hv.y);
    unsafeAtomicAdd(ap + 2, ex * hv.z);
    unsafeAtomicAdd(ap + 3, ex * hv.w);
}

// ---------------- finalize layer2 + log_softmax ----------------
__global__ __launch_bounds__(256) void logsm(
    const float* __restrict__ acc2, const float* __restrict__ denom2,
    const float* __restrict__ b2, float* __restrict__ out, int n)
{
    int t = blockIdx.x * blockDim.x + threadIdx.x;
    int node = t >> 4;
    int j = t & 15;
    if (node >= n) return;
    float v = acc2[node * 16 + j] / (denom2[node] + 1e-16f) + b2[j];
    float m = v;
    #pragma unroll
    for (int o = 8; o; o >>= 1) m = fmaxf(m, __shfl_xor(m, o, 16));
    float s = __expf(v - m);
    #pragma unroll
    for (int o = 8; o; o >>= 1) s += __shfl_xor(s, o, 16);
    out[node * 16 + j] = v - m - logf(s);
}

extern "C" void kernel_launch(void* const* d_in, const int* in_sizes, int n_in,
                              void* d_out, int out_size, void* d_ws, size_t ws_size,
                              hipStream_t stream) {
    const float* x        = (const float*)d_in[0];
    const int*   ei       = (const int*)d_in[1];
    const float* W1       = (const float*)d_in[2];
    const float* att_src1 = (const float*)d_in[3];
    const float* att_dst1 = (const float*)d_in[4];
    const float* b1       = (const float*)d_in[5];
    const float* W2       = (const float*)d_in[6];
    const float* att_src2 = (const float*)d_in[7];
    const float* att_dst2 = (const float*)d_in[8];
    const float* b2       = (const float*)d_in[9];
    float* out = (float*)d_out;

    const int n = in_sizes[0] / 512;
    const int E = in_sizes[1] / 2;

    // workspace layout (floats)
    float* ws     = (float*)d_ws;
    float* h1     = ws;                    // n*64
    float* asrc1  = h1    + (size_t)n * 64;  // n*8
    float* adst1  = asrc1 + (size_t)n * 8;   // n*8
    float* denom1 = adst1 + (size_t)n * 8;   // n*8
    float* acc1   = denom1+ (size_t)n * 8;   // n*64  (becomes h2in after finalize1)
    float* h2     = acc1  + (size_t)n * 64;  // n*16
    float* asrc2  = h2    + (size_t)n * 16;  // n
    float* adst2  = asrc2 + (size_t)n;       // n
    float* denom2 = adst2 + (size_t)n;       // n
    float* acc2   = denom2+ (size_t)n;       // n*16

    // zero denom1+acc1 (contiguous) and denom2+acc2 (contiguous)
    hipMemsetAsync(denom1, 0, (size_t)n * 72 * sizeof(float), stream);
    hipMemsetAsync(denom2, 0, (size_t)n * 17 * sizeof(float), stream);

    // layer 1
    int blocks1 = (n + 63) / 64;
    gemm1_att<<<blocks1, 256, 0, stream>>>(x, W1, att_src1, att_dst1, h1, asrc1, adst1, n);

    long long te1 = (long long)(E + n) * 8;
    edge1<<<(int)((te1 + 255) / 256), 256, 0, stream>>>(ei, asrc1, adst1, h1, denom1, acc1, E, n);

    int tf1 = n * 64;
    finalize1<<<(tf1 + 255) / 256, 256, 0, stream>>>(acc1, denom1, b1, n);

    // layer 2
    gemm2_att<<<(n + 15) / 16, 256, 0, stream>>>(acc1, W2, att_src2, att_dst2, h2, asrc2, adst2, n);

    long long te2 = (long long)(E + n) * 4;
    edge2<<<(int)((te2 + 255) / 256), 256, 0, stream>>>(ei, asrc2, adst2, h2, denom2, acc2, E, n);

    int tl = n * 16;
    logsm<<<(tl + 255) / 256, 256, 0, stream>>>(acc2, denom2, b2, out, n);
}

// Round 2
// 760.335 us; speedup vs baseline: 4.8742x; 4.8742x over previous
//
#include <hip/hip_runtime.h>
#include <hip/hip_bf16.h>

#define NEG_SLOPE 0.2f

// ---------------- GEMM1: h1 = x @ W1  [n,512]x[512,64], fused att reductions ----------------
__global__ __launch_bounds__(256) void gemm1_att(
    const float* __restrict__ x, const float* __restrict__ W,
    const float* __restrict__ att_src, const float* __restrict__ att_dst,
    float* __restrict__ h1, float* __restrict__ asrc, float* __restrict__ adst, int n)
{
    __shared__ float As[64][65];   // [k][row], pad 65 to break bank conflicts
    __shared__ float Bs[64][64];   // [k][col]
    const int t  = threadIdx.x;
    const int rb = blockIdx.x * 64;
    const int ty = t >> 4;         // 0..15 -> row group
    const int tx = t & 15;         // 0..15 -> col group
    float acc[4][4] = {};

    for (int k0 = 0; k0 < 512; k0 += 64) {
        #pragma unroll
        for (int rr = 0; rr < 4; ++rr) {
            int r = (t >> 4) + rr * 16;
            int c = (t & 15) * 4;
            float4 v = make_float4(0.f, 0.f, 0.f, 0.f);
            int gr = rb + r;
            if (gr < n) v = *(const float4*)(x + (size_t)gr * 512 + k0 + c);
            As[c + 0][r] = v.x; As[c + 1][r] = v.y; As[c + 2][r] = v.z; As[c + 3][r] = v.w;
        }
        #pragma unroll
        for (int rr = 0; rr < 4; ++rr) {
            int kk = (t >> 4) + rr * 16;
            int c  = (t & 15) * 4;
            *(float4*)&Bs[kk][c] = *(const float4*)(W + (size_t)(k0 + kk) * 64 + c);
        }
        __syncthreads();
        #pragma unroll
        for (int kk = 0; kk < 64; ++kk) {
            float a0 = As[kk][ty * 4 + 0];
            float a1 = As[kk][ty * 4 + 1];
            float a2 = As[kk][ty * 4 + 2];
            float a3 = As[kk][ty * 4 + 3];
            float4 b = *(const float4*)&Bs[kk][tx * 4];
            acc[0][0] += a0 * b.x; acc[0][1] += a0 * b.y; acc[0][2] += a0 * b.z; acc[0][3] += a0 * b.w;
            acc[1][0] += a1 * b.x; acc[1][1] += a1 * b.y; acc[1][2] += a1 * b.z; acc[1][3] += a1 * b.w;
            acc[2][0] += a2 * b.x; acc[2][1] += a2 * b.y; acc[2][2] += a2 * b.z; acc[2][3] += a2 * b.w;
            acc[3][0] += a3 * b.x; acc[3][1] += a3 * b.y; acc[3][2] += a3 * b.z; acc[3][3] += a3 * b.w;
        }
        __syncthreads();
    }

    const int head = tx >> 1;
    const int halfoff = (tx & 1) * 4;
    #pragma unroll
    for (int i = 0; i < 4; ++i) {
        int gr = rb + ty * 4 + i;
        float ps = acc[i][0] * att_src[head * 8 + halfoff + 0]
                 + acc[i][1] * att_src[head * 8 + halfoff + 1]
                 + acc[i][2] * att_src[head * 8 + halfoff + 2]
                 + acc[i][3] * att_src[head * 8 + halfoff + 3];
        float pd = acc[i][0] * att_dst[head * 8 + halfoff + 0]
                 + acc[i][1] * att_dst[head * 8 + halfoff + 1]
                 + acc[i][2] * att_dst[head * 8 + halfoff + 2]
                 + acc[i][3] * att_dst[head * 8 + halfoff + 3];
        ps += __shfl_xor(ps, 1);
        pd += __shfl_xor(pd, 1);
        if (gr < n) {
            *(float4*)(h1 + (size_t)gr * 64 + tx * 4) = make_float4(acc[i][0], acc[i][1], acc[i][2], acc[i][3]);
            if ((tx & 1) == 0) {
                asrc[gr * 8 + head] = ps;
                adst[gr * 8 + head] = pd;
            }
        }
    }
}

// ---------------- CSR build: histogram over dst ----------------
__global__ __launch_bounds__(256) void hist_k(const int* __restrict__ ei, int* __restrict__ cnt, int E)
{
    int t = blockIdx.x * blockDim.x + threadIdx.x;
    if (t < E) atomicAdd(&cnt[ei[E + t]], 1);
}

// single-block exclusive scan (n up to ~1M fine)
__global__ __launch_bounds__(1024) void scan_k(const int* __restrict__ cnt, int* __restrict__ rowptr, int n, int E)
{
    __shared__ int part[1024];
    const int t = threadIdx.x;
    const int chunk = (n + 1023) >> 10;
    const int lo = t * chunk;
    const int hi = min(n, lo + chunk);
    int s = 0;
    for (int i = lo; i < hi; ++i) s += cnt[i];
    part[t] = s;
    __syncthreads();
    for (int o = 1; o < 1024; o <<= 1) {
        int v = (t >= o) ? part[t - o] : 0;
        __syncthreads();
        part[t] += v;
        __syncthreads();
    }
    int excl = (t == 0) ? 0 : part[t - 1];
    for (int i = lo; i < hi; ++i) { rowptr[i] = excl; excl += cnt[i]; }
    if (t == 1023) rowptr[n] = E;
}

// scatter src ids into dst-sorted order
__global__ __launch_bounds__(256) void scatter_k(
    const int* __restrict__ ei, const int* __restrict__ rowptr,
    int* __restrict__ off, int* __restrict__ ssrc, int E)
{
    int t = blockIdx.x * blockDim.x + threadIdx.x;
    if (t >= E) return;
    int d = ei[E + t];
    int p = rowptr[d] + atomicAdd(&off[d], 1);
    ssrc[p] = ei[t];
}

// ---------------- layer1 aggregate + finalize + GEMM2 + att2, one wave per node ----------------
__global__ __launch_bounds__(256) void agg1_k(
    const int* __restrict__ rowptr, const int* __restrict__ ssrc,
    const float* __restrict__ asrc1, const float* __restrict__ adst1,
    const float* __restrict__ h1, const float* __restrict__ b1,
    const float* __restrict__ W2, const float* __restrict__ att_src2, const float* __restrict__ att_dst2,
    float* __restrict__ h2, float* __restrict__ asrc2, float* __restrict__ adst2, int n)
{
    __shared__ float Ws2[64 * 17];       // padded [64][17] to break bank conflicts
    __shared__ float sv[4][64];
    const int t = threadIdx.x;
    // cooperative W2 load (64x16)
    #pragma unroll
    for (int k = 0; k < 4; ++k) {
        int idx = t + k * 256;
        Ws2[(idx >> 4) * 17 + (idx & 15)] = W2[idx];
    }
    __syncthreads();

    const int wv = t >> 6;
    const int j  = t & 63;
    const int h  = j >> 3;
    const int node = blockIdx.x * 4 + wv;
    const bool active = node < n;

    float v = 0.f;
    if (active) {
        const int d = node;
        const int start = rowptr[d], end = rowptr[d + 1];
        float adstj = (j < 8) ? adst1[d * 8 + j] : 0.f;
        float acc = 0.f, dsum = 0.f;
        for (int i = start - 1; i < end; ++i) {       // i==start-1 is the self-loop
            int s = (i < start) ? d : ssrc[i];
            float ex = 0.f;
            if (j < 8) {
                float e = asrc1[s * 8 + j] + adstj;
                e = e > 0.f ? e : NEG_SLOPE * e;
                ex = __expf(e);
                dsum += ex;
            }
            float exh = __shfl(ex, h);
            acc += exh * h1[(size_t)s * 64 + j];
        }
        float den = __shfl(dsum, h) + 1e-16f;
        v = acc / den + b1[j];
        v = v > 0.f ? v : (__expf(v) - 1.f);          // ELU
    }
    sv[wv][j] = v;
    __syncthreads();

    if (active) {
        // GEMM2: h2[node,c] = sum_r v_r * W2[r,c]; lane j handles c=j&15, quarter q=j>>4
        const int c = j & 15, q = j >> 4;
        float p = 0.f;
        #pragma unroll
        for (int r = 0; r < 16; ++r)
            p += sv[wv][q * 16 + r] * Ws2[(q * 16 + r) * 17 + c];
        p += __shfl_xor(p, 16);
        p += __shfl_xor(p, 32);                        // all lanes now hold channel (j&15) total
        if (j < 16) h2[(size_t)node * 16 + j] = p;
        float as2 = p * att_src2[c];
        float ad2 = p * att_dst2[c];
        #pragma unroll
        for (int o = 1; o < 16; o <<= 1) { as2 += __shfl_xor(as2, o, 16); ad2 += __shfl_xor(ad2, o, 16); }
        if (j == 0) { asrc2[node] = as2; adst2[node] = ad2; }
    }
}

// ---------------- layer2 aggregate + log_softmax, one wave per node ----------------
__global__ __launch_bounds__(256) void agg2_k(
    const int* __restrict__ rowptr, const int* __restrict__ ssrc,
    const float* __restrict__ asrc2, const float* __restrict__ adst2,
    const float* __restrict__ h2, const float* __restrict__ b2,
    float* __restrict__ out, int n)
{
    const int t = threadIdx.x;
    const int node = blockIdx.x * 4 + (t >> 6);
    if (node >= n) return;
    const int j = t & 63;
    const int sub = j >> 4, c = j & 15;
    const int d = node;
    const int start = rowptr[d], end = rowptr[d + 1];
    const float adst_d = adst2[d];

    float acc = 0.f, dsum = 0.f;
    if (sub == 0) {                                    // self-loop
        float e = asrc2[d] + adst_d;
        e = e > 0.f ? e : NEG_SLOPE * e;
        float ex = __expf(e);
        acc += ex * h2[(size_t)d * 16 + c];
        dsum += ex;
    }
    for (int i = start + sub; i < end; i += 4) {
        int s = ssrc[i];
        float e = asrc2[s] + adst_d;
        e = e > 0.f ? e : NEG_SLOPE * e;
        float ex = __expf(e);
        acc += ex * h2[(size_t)s * 16 + c];
        dsum += ex;
    }
    acc += __shfl_xor(acc, 16);  acc += __shfl_xor(acc, 32);
    dsum += __shfl_xor(dsum, 16); dsum += __shfl_xor(dsum, 32);

    float v = acc / (dsum + 1e-16f) + b2[c];
    float m = v;
    #pragma unroll
    for (int o = 1; o < 16; o <<= 1) m = fmaxf(m, __shfl_xor(m, o, 16));
    float s2 = __expf(v - m);
    #pragma unroll
    for (int o = 1; o < 16; o <<= 1) s2 += __shfl_xor(s2, o, 16);
    if (j < 16) out[(size_t)d * 16 + j] = v - m - logf(s2);
}

extern "C" void kernel_launch(void* const* d_in, const int* in_sizes, int n_in,
                              void* d_out, int out_size, void* d_ws, size_t ws_size,
                              hipStream_t stream) {
    const float* x        = (const float*)d_in[0];
    const int*   ei       = (const int*)d_in[1];
    const float* W1       = (const float*)d_in[2];
    const float* att_src1 = (const float*)d_in[3];
    const float* att_dst1 = (const float*)d_in[4];
    const float* b1       = (const float*)d_in[5];
    const float* W2       = (const float*)d_in[6];
    const float* att_src2 = (const float*)d_in[7];
    const float* att_dst2 = (const float*)d_in[8];
    const float* b2       = (const float*)d_in[9];
    float* out = (float*)d_out;

    const int n = in_sizes[0] / 512;
    const int E = in_sizes[1] / 2;

    // workspace layout
    float* ws     = (float*)d_ws;
    float* h1     = ws;                        // 64n
    float* asrc1  = h1    + (size_t)n * 64;    // 8n
    float* adst1  = asrc1 + (size_t)n * 8;     // 8n
    float* h2     = adst1 + (size_t)n * 8;     // 16n
    float* asrc2  = h2    + (size_t)n * 16;    // n
    float* adst2  = asrc2 + (size_t)n;         // n
    int*   rowptr = (int*)(adst2 + (size_t)n); // n+1
    int*   cnt    = rowptr + (n + 1);          // n
    int*   off    = cnt + n;                   // n
    int*   ssrc   = off + n;                   // E

    hipMemsetAsync(cnt, 0, (size_t)2 * n * sizeof(int), stream);   // cnt + off

    // CSR build
    hist_k<<<(E + 255) / 256, 256, 0, stream>>>(ei, cnt, E);
    scan_k<<<1, 1024, 0, stream>>>(cnt, rowptr, n, E);
    scatter_k<<<(E + 255) / 256, 256, 0, stream>>>(ei, rowptr, off, ssrc, E);

    // layer 1 GEMM + att
    gemm1_att<<<(n + 63) / 64, 256, 0, stream>>>(x, W1, att_src1, att_dst1, h1, asrc1, adst1, n);

    // layer1 aggregate (+finalize+GEMM2+att2 fused)
    agg1_k<<<(n + 3) / 4, 256, 0, stream>>>(rowptr, ssrc, asrc1, adst1, h1, b1,
                                            W2, att_src2, att_dst2, h2, asrc2, adst2, n);

    // layer2 aggregate + log_softmax
    agg2_k<<<(n + 3) / 4, 256, 0, stream>>>(rowptr, ssrc, asrc2, adst2, h2, b2, out, n);
}

// Round 3
// 703.134 us; speedup vs baseline: 5.2707x; 1.0814x over previous
//
#include <hip/hip_runtime.h>
#include <hip/hip_bf16.h>

#define NEG_SLOPE 0.2f

typedef __attribute__((ext_vector_type(8))) short  bf16x8;
typedef __attribute__((ext_vector_type(8))) unsigned short u16x8;
typedef __attribute__((ext_vector_type(4))) float  f32x4;

static __device__ __forceinline__ ushort f2bf(float f) {
    union { float f; unsigned int u; } c; c.f = f;
    unsigned int r = c.u + 0x7fffu + ((c.u >> 16) & 1u);   // round-to-nearest-even
    return (ushort)(r >> 16);
}
static __device__ __forceinline__ float bf2f(ushort u) {
    union { unsigned int u; float f; } c; c.u = ((unsigned int)u) << 16;
    return c.f;
}

// ---------------- GEMM1 via bf16 MFMA: h1b = bf16(x @ W1) ----------------
__global__ __launch_bounds__(256) void gemm1_mfma(
    const float* __restrict__ x, const float* __restrict__ W,
    ushort* __restrict__ h1b, int n)
{
    __shared__ ushort Bs[64][520];  // W1 transposed [col][k], bf16, row stride 1040B (16B-aligned, 2-way banks)
    __shared__ ushort As[64][72];   // x tile [row][kk], bf16, row stride 144B
    const int t    = threadIdx.x;
    const int lane = t & 63;
    const int wv   = t >> 6;
    const int rb   = blockIdx.x * 64;
    const int m    = lane & 15;
    const int kg   = lane >> 4;

    // stage all of W1 (512x64 f32) -> Bs[col][k] bf16 (once)
    #pragma unroll 4
    for (int i = 0; i < 32; ++i) {
        int idx = (t + i * 256) * 4;
        float4 v = *(const float4*)(W + idx);
        int k = idx >> 6, c = idx & 63;
        Bs[c + 0][k] = f2bf(v.x); Bs[c + 1][k] = f2bf(v.y);
        Bs[c + 2][k] = f2bf(v.z); Bs[c + 3][k] = f2bf(v.w);
    }
    f32x4 acc[4] = {};
    __syncthreads();

    for (int kc = 0; kc < 512; kc += 64) {
        // stage A: 64 rows x 64 k -> bf16
        {
            int r = t >> 2, kq = (t & 3) * 16;
            int gr = rb + r;
            float4 a = {}, b = {}, c4 = {}, d4 = {};
            if (gr < n) {
                const float* p = x + (size_t)gr * 512 + kc + kq;
                a  = *(const float4*)(p);
                b  = *(const float4*)(p + 4);
                c4 = *(const float4*)(p + 8);
                d4 = *(const float4*)(p + 12);
            }
            u16x8 u0, u1;
            u0[0]=f2bf(a.x);  u0[1]=f2bf(a.y);  u0[2]=f2bf(a.z);  u0[3]=f2bf(a.w);
            u0[4]=f2bf(b.x);  u0[5]=f2bf(b.y);  u0[6]=f2bf(b.z);  u0[7]=f2bf(b.w);
            u1[0]=f2bf(c4.x); u1[1]=f2bf(c4.y); u1[2]=f2bf(c4.z); u1[3]=f2bf(c4.w);
            u1[4]=f2bf(d4.x); u1[5]=f2bf(d4.y); u1[6]=f2bf(d4.z); u1[7]=f2bf(d4.w);
            *(u16x8*)&As[r][kq]     = u0;
            *(u16x8*)&As[r][kq + 8] = u1;
        }
        __syncthreads();
        #pragma unroll
        for (int ks = 0; ks < 2; ++ks) {
            bf16x8 af = *(const bf16x8*)&As[wv * 16 + m][ks * 32 + kg * 8];
            #pragma unroll
            for (int t4 = 0; t4 < 4; ++t4) {
                bf16x8 bfr = *(const bf16x8*)&Bs[t4 * 16 + m][kc + ks * 32 + kg * 8];
                acc[t4] = __builtin_amdgcn_mfma_f32_16x16x32_bf16(af, bfr, acc[t4], 0, 0, 0);
            }
        }
        __syncthreads();
    }

    // C/D layout: col = lane&15, row = (lane>>4)*4 + reg   [verified mapping]
    #pragma unroll
    for (int t4 = 0; t4 < 4; ++t4)
        #pragma unroll
        for (int i = 0; i < 4; ++i) {
            int gr = rb + wv * 16 + kg * 4 + i;
            if (gr < n) h1b[(size_t)gr * 64 + t4 * 16 + m] = f2bf(acc[t4][i]);
        }
}

// ---------------- att1: asrc/adst from h1b ----------------
__global__ __launch_bounds__(256) void att1_k(
    const ushort* __restrict__ h1b, const float* __restrict__ as, const float* __restrict__ ad,
    float* __restrict__ asrc, float* __restrict__ adst, int n)
{
    int idx = blockIdx.x * 256 + threadIdx.x;
    if (idx >= n * 64) return;
    int j = idx & 63;
    float v = bf2f(h1b[idx]);
    float ps = v * as[j], pd = v * ad[j];
    ps += __shfl_xor(ps, 1); pd += __shfl_xor(pd, 1);
    ps += __shfl_xor(ps, 2); pd += __shfl_xor(pd, 2);
    ps += __shfl_xor(ps, 4); pd += __shfl_xor(pd, 4);
    if ((j & 7) == 0) {
        int node = idx >> 6;
        asrc[node * 8 + (j >> 3)] = ps;
        adst[node * 8 + (j >> 3)] = pd;
    }
}

// ---------------- CSR build ----------------
__global__ __launch_bounds__(256) void hist_k(const int* __restrict__ ei, int* __restrict__ cnt, int E)
{
    int t = blockIdx.x * blockDim.x + threadIdx.x;
    if (t < E) atomicAdd(&cnt[ei[E + t]], 1);
}

__global__ __launch_bounds__(1024) void scan_k(const int* __restrict__ cnt, int* __restrict__ rowptr, int n, int E)
{
    __shared__ int part[1024];
    const int t = threadIdx.x;
    const int chunk = (n + 1023) >> 10;
    const int lo = t * chunk;
    const int hi = min(n, lo + chunk);
    int s = 0;
    for (int i = lo; i < hi; ++i) s += cnt[i];
    part[t] = s;
    __syncthreads();
    for (int o = 1; o < 1024; o <<= 1) {
        int v = (t >= o) ? part[t - o] : 0;
        __syncthreads();
        part[t] += v;
        __syncthreads();
    }
    int excl = (t == 0) ? 0 : part[t - 1];
    for (int i = lo; i < hi; ++i) { rowptr[i] = excl; excl += cnt[i]; }
    if (t == 1023) rowptr[n] = E;
}

__global__ __launch_bounds__(256) void scatter_k(
    const int* __restrict__ ei, const int* __restrict__ rowptr,
    int* __restrict__ off, int* __restrict__ ssrc, int E)
{
    int t = blockIdx.x * blockDim.x + threadIdx.x;
    if (t >= E) return;
    int d = ei[E + t];
    int p = rowptr[d] + atomicAdd(&off[d], 1);
    ssrc[p] = ei[t];
}

// ---------------- layer1 aggregate + ELU + GEMM2 + att2, one wave per node ----------------
__global__ __launch_bounds__(256) void agg1_k(
    const int* __restrict__ rowptr, const int* __restrict__ ssrc,
    const float* __restrict__ asrc1, const float* __restrict__ adst1,
    const ushort* __restrict__ h1b, const float* __restrict__ b1,
    const float* __restrict__ W2, const float* __restrict__ att_src2, const float* __restrict__ att_dst2,
    ushort* __restrict__ h2b, float* __restrict__ asrc2, float* __restrict__ adst2, int n)
{
    __shared__ float Ws2[64 * 17];
    __shared__ float sv[4][64];
    const int t = threadIdx.x;
    #pragma unroll
    for (int k = 0; k < 4; ++k) {
        int idx = t + k * 256;
        Ws2[(idx >> 4) * 17 + (idx & 15)] = W2[idx];
    }
    __syncthreads();

    const int wv = t >> 6;
    const int j  = t & 63;
    const int h  = j >> 3;
    const int node = blockIdx.x * 4 + wv;
    const bool active = node < n;

    float v = 0.f;
    if (active) {
        const int d = node;
        const int start = rowptr[d], end = rowptr[d + 1];
        float adstj = (j < 8) ? adst1[d * 8 + j] : 0.f;
        float acc = 0.f, dsum = 0.f;
        for (int i = start - 1; i < end; ++i) {       // i==start-1 is the self-loop
            int s = (i < start) ? d : ssrc[i];
            float ex = 0.f;
            if (j < 8) {
                float e = asrc1[s * 8 + j] + adstj;
                e = e > 0.f ? e : NEG_SLOPE * e;
                ex = __expf(e);
                dsum += ex;
            }
            float exh = __shfl(ex, h);
            acc += exh * bf2f(h1b[(size_t)s * 64 + j]);
        }
        float den = __shfl(dsum, h) + 1e-16f;
        v = acc / den + b1[j];
        v = v > 0.f ? v : (__expf(v) - 1.f);          // ELU
    }
    sv[wv][j] = v;
    __syncthreads();

    if (active) {
        const int c = j & 15, q = j >> 4;
        float p = 0.f;
        #pragma unroll
        for (int r = 0; r < 16; ++r)
            p += sv[wv][q * 16 + r] * Ws2[(q * 16 + r) * 17 + c];
        p += __shfl_xor(p, 16);
        p += __shfl_xor(p, 32);
        if (j < 16) h2b[(size_t)node * 16 + j] = f2bf(p);
        float as2 = p * att_src2[c];
        float ad2 = p * att_dst2[c];
        #pragma unroll
        for (int o = 1; o < 16; o <<= 1) { as2 += __shfl_xor(as2, o, 16); ad2 += __shfl_xor(ad2, o, 16); }
        if (j == 0) { asrc2[node] = as2; adst2[node] = ad2; }
    }
}

// ---------------- layer2 aggregate + log_softmax, one wave per node ----------------
__global__ __launch_bounds__(256) void agg2_k(
    const int* __restrict__ rowptr, const int* __restrict__ ssrc,
    const float* __restrict__ asrc2, const float* __restrict__ adst2,
    const ushort* __restrict__ h2b, const float* __restrict__ b2,
    float* __restrict__ out, int n)
{
    const int t = threadIdx.x;
    const int node = blockIdx.x * 4 + (t >> 6);
    if (node >= n) return;
    const int j = t & 63;
    const int sub = j >> 4, c = j & 15;
    const int d = node;
    const int start = rowptr[d], end = rowptr[d + 1];
    const float adst_d = adst2[d];

    float acc = 0.f, dsum = 0.f;
    if (sub == 0) {                                    // self-loop
        float e = asrc2[d] + adst_d;
        e = e > 0.f ? e : NEG_SLOPE * e;
        float ex = __expf(e);
        acc += ex * bf2f(h2b[(size_t)d * 16 + c]);
        dsum += ex;
    }
    for (int i = start + sub; i < end; i += 4) {
        int s = ssrc[i];
        float e = asrc2[s] + adst_d;
        e = e > 0.f ? e : NEG_SLOPE * e;
        float ex = __expf(e);
        acc += ex * bf2f(h2b[(size_t)s * 16 + c]);
        dsum += ex;
    }
    acc  += __shfl_xor(acc, 16);  acc  += __shfl_xor(acc, 32);
    dsum += __shfl_xor(dsum, 16); dsum += __shfl_xor(dsum, 32);

    float v = acc / (dsum + 1e-16f) + b2[c];
    float m = v;
    #pragma unroll
    for (int o = 1; o < 16; o <<= 1) m = fmaxf(m, __shfl_xor(m, o, 16));
    float s2 = __expf(v - m);
    #pragma unroll
    for (int o = 1; o < 16; o <<= 1) s2 += __shfl_xor(s2, o, 16);
    if (j < 16) out[(size_t)d * 16 + j] = v - m - logf(s2);
}

extern "C" void kernel_launch(void* const* d_in, const int* in_sizes, int n_in,
                              void* d_out, int out_size, void* d_ws, size_t ws_size,
                              hipStream_t stream) {
    const float* x        = (const float*)d_in[0];
    const int*   ei       = (const int*)d_in[1];
    const float* W1       = (const float*)d_in[2];
    const float* att_src1 = (const float*)d_in[3];
    const float* att_dst1 = (const float*)d_in[4];
    const float* b1       = (const float*)d_in[5];
    const float* W2       = (const float*)d_in[6];
    const float* att_src2 = (const float*)d_in[7];
    const float* att_dst2 = (const float*)d_in[8];
    const float* b2       = (const float*)d_in[9];
    float* out = (float*)d_out;

    const int n = in_sizes[0] / 512;
    const int E = in_sizes[1] / 2;

    // workspace layout (bytes)
    char* base = (char*)d_ws;
    ushort* h1b   = (ushort*)(base);                          // 128n B
    ushort* h2b   = (ushort*)(base + (size_t)128 * n);        // 32n B
    float*  asrc1 = (float*) (base + (size_t)160 * n);        // 32n B
    float*  adst1 = (float*) (base + (size_t)192 * n);        // 32n B
    float*  asrc2 = (float*) (base + (size_t)224 * n);        // 4n B
    float*  adst2 = (float*) (base + (size_t)228 * n);        // 4n B
    int*    rowptr= (int*)   (base + (size_t)232 * n);        // 4n+4 B
    int*    cnt   = (int*)   (base + (size_t)236 * n + 4);    // 4n B
    int*    off   = (int*)   (base + (size_t)240 * n + 4);    // 4n B
    int*    ssrc  = (int*)   (base + (size_t)244 * n + 4);    // 4E B

    hipMemsetAsync(cnt, 0, (size_t)8 * n, stream);   // cnt + off

    // CSR build
    hist_k<<<(E + 255) / 256, 256, 0, stream>>>(ei, cnt, E);
    scan_k<<<1, 1024, 0, stream>>>(cnt, rowptr, n, E);
    scatter_k<<<(E + 255) / 256, 256, 0, stream>>>(ei, rowptr, off, ssrc, E);

    // layer 1 GEMM (MFMA) + att reductions
    gemm1_mfma<<<(n + 63) / 64, 256, 0, stream>>>(x, W1, h1b, n);
    att1_k<<<(n * 64 + 255) / 256, 256, 0, stream>>>(h1b, att_src1, att_dst1, asrc1, adst1, n);

    // layer1 aggregate (+ELU+GEMM2+att2 fused)
    agg1_k<<<(n + 3) / 4, 256, 0, stream>>>(rowptr, ssrc, asrc1, adst1, h1b, b1,
                                            W2, att_src2, att_dst2, h2b, asrc2, adst2, n);

    // layer2 aggregate + log_softmax
    agg2_k<<<(n + 3) / 4, 256, 0, stream>>>(rowptr, ssrc, asrc2, adst2, h2b, b2, out, n);
}

// Round 4
// 517.984 us; speedup vs baseline: 7.1547x; 1.3574x over previous
//
#include <hip/hip_runtime.h>
#include <hip/hip_bf16.h>

#define NEG_SLOPE 0.2f

typedef __attribute__((ext_vector_type(8))) short  bf16x8;
typedef __attribute__((ext_vector_type(8))) unsigned short u16x8;
typedef __attribute__((ext_vector_type(4))) unsigned short u16x4;
typedef __attribute__((ext_vector_type(4))) float  f32x4;

static __device__ __forceinline__ ushort f2bf(float f) {
    union { float f; unsigned int u; } c; c.f = f;
    unsigned int r = c.u + 0x7fffu + ((c.u >> 16) & 1u);   // round-to-nearest-even
    return (ushort)(r >> 16);
}
static __device__ __forceinline__ float bf2f(ushort u) {
    union { unsigned int u; float f; } c; c.u = ((unsigned int)u) << 16;
    return c.f;
}

// ---------------- GEMM1 via bf16 MFMA: h1b = bf16(x @ W1) ----------------
__global__ __launch_bounds__(256) void gemm1_mfma(
    const float* __restrict__ x, const float* __restrict__ W,
    ushort* __restrict__ h1b, int n)
{
    __shared__ ushort Bs[64][520];  // W1 transposed [col][k], bf16
    __shared__ ushort As[64][72];   // x tile [row][kk], bf16
    const int t    = threadIdx.x;
    const int lane = t & 63;
    const int wv   = t >> 6;
    const int rb   = blockIdx.x * 64;
    const int m    = lane & 15;
    const int kg   = lane >> 4;

    #pragma unroll 4
    for (int i = 0; i < 32; ++i) {
        int idx = (t + i * 256) * 4;
        float4 v = *(const float4*)(W + idx);
        int k = idx >> 6, c = idx & 63;
        Bs[c + 0][k] = f2bf(v.x); Bs[c + 1][k] = f2bf(v.y);
        Bs[c + 2][k] = f2bf(v.z); Bs[c + 3][k] = f2bf(v.w);
    }
    f32x4 acc[4] = {};
    __syncthreads();

    for (int kc = 0; kc < 512; kc += 64) {
        {
            int r = t >> 2, kq = (t & 3) * 16;
            int gr = rb + r;
            float4 a = {}, b = {}, c4 = {}, d4 = {};
            if (gr < n) {
                const float* p = x + (size_t)gr * 512 + kc + kq;
                a  = *(const float4*)(p);
                b  = *(const float4*)(p + 4);
                c4 = *(const float4*)(p + 8);
                d4 = *(const float4*)(p + 12);
            }
            u16x8 u0, u1;
            u0[0]=f2bf(a.x);  u0[1]=f2bf(a.y);  u0[2]=f2bf(a.z);  u0[3]=f2bf(a.w);
            u0[4]=f2bf(b.x);  u0[5]=f2bf(b.y);  u0[6]=f2bf(b.z);  u0[7]=f2bf(b.w);
            u1[0]=f2bf(c4.x); u1[1]=f2bf(c4.y); u1[2]=f2bf(c4.z); u1[3]=f2bf(c4.w);
            u1[4]=f2bf(d4.x); u1[5]=f2bf(d4.y); u1[6]=f2bf(d4.z); u1[7]=f2bf(d4.w);
            *(u16x8*)&As[r][kq]     = u0;
            *(u16x8*)&As[r][kq + 8] = u1;
        }
        __syncthreads();
        #pragma unroll
        for (int ks = 0; ks < 2; ++ks) {
            bf16x8 af = *(const bf16x8*)&As[wv * 16 + m][ks * 32 + kg * 8];
            #pragma unroll
            for (int t4 = 0; t4 < 4; ++t4) {
                bf16x8 bfr = *(const bf16x8*)&Bs[t4 * 16 + m][kc + ks * 32 + kg * 8];
                acc[t4] = __builtin_amdgcn_mfma_f32_16x16x32_bf16(af, bfr, acc[t4], 0, 0, 0);
            }
        }
        __syncthreads();
    }

    #pragma unroll
    for (int t4 = 0; t4 < 4; ++t4)
        #pragma unroll
        for (int i = 0; i < 4; ++i) {
            int gr = rb + wv * 16 + kg * 4 + i;
            if (gr < n) h1b[(size_t)gr * 64 + t4 * 16 + m] = f2bf(acc[t4][i]);
        }
}

// ---------------- att1: asrc/adst from h1b ----------------
__global__ __launch_bounds__(256) void att1_k(
    const ushort* __restrict__ h1b, const float* __restrict__ as, const float* __restrict__ ad,
    float* __restrict__ asrc, float* __restrict__ adst, int n)
{
    int idx = blockIdx.x * 256 + threadIdx.x;
    if (idx >= n * 64) return;
    int j = idx & 63;
    float v = bf2f(h1b[idx]);
    float ps = v * as[j], pd = v * ad[j];
    ps += __shfl_xor(ps, 1); pd += __shfl_xor(pd, 1);
    ps += __shfl_xor(ps, 2); pd += __shfl_xor(pd, 2);
    ps += __shfl_xor(ps, 4); pd += __shfl_xor(pd, 4);
    if ((j & 7) == 0) {
        int node = idx >> 6;
        asrc[node * 8 + (j >> 3)] = ps;
        adst[node * 8 + (j >> 3)] = pd;
    }
}

// ---------------- CSR build ----------------
__global__ __launch_bounds__(256) void hist_k(const int* __restrict__ ei, int* __restrict__ cnt, int E)
{
    int t = blockIdx.x * blockDim.x + threadIdx.x;
    if (t < E) atomicAdd(&cnt[ei[E + t]], 1);
}

__global__ __launch_bounds__(1024) void scan_k(const int* __restrict__ cnt, int* __restrict__ rowptr, int n, int E)
{
    __shared__ int part[1024];
    const int t = threadIdx.x;
    const int chunk = (n + 1023) >> 10;
    const int lo = t * chunk;
    const int hi = min(n, lo + chunk);
    int s = 0;
    for (int i = lo; i < hi; ++i) s += cnt[i];
    part[t] = s;
    __syncthreads();
    for (int o = 1; o < 1024; o <<= 1) {
        int v = (t >= o) ? part[t - o] : 0;
        __syncthreads();
        part[t] += v;
        __syncthreads();
    }
    int excl = (t == 0) ? 0 : part[t - 1];
    for (int i = lo; i < hi; ++i) { rowptr[i] = excl; excl += cnt[i]; }
    if (t == 1023) rowptr[n] = E;
}

__global__ __launch_bounds__(256) void scatter_k(
    const int* __restrict__ ei, const int* __restrict__ rowptr,
    int* __restrict__ off, int* __restrict__ ssrc, int E)
{
    int t = blockIdx.x * blockDim.x + threadIdx.x;
    if (t >= E) return;
    int d = ei[E + t];
    int p = rowptr[d] + atomicAdd(&off[d], 1);
    ssrc[p] = ei[t];
}

// ---------------- layer1 aggregate + ELU + GEMM2 + att2 ----------------
// one wave per node; 8 edges in flight (g=lane>>3), lane handles head h=lane&7's 8 channels
__global__ __launch_bounds__(256) void agg1_k(
    const int* __restrict__ rowptr, const int* __restrict__ ssrc,
    const float* __restrict__ asrc1, const float* __restrict__ adst1,
    const ushort* __restrict__ h1b, const float* __restrict__ b1,
    const float* __restrict__ W2, const float* __restrict__ att_src2, const float* __restrict__ att_dst2,
    ushort* __restrict__ h2b, float* __restrict__ asrc2, float* __restrict__ adst2, int n)
{
    __shared__ float Ws2[64 * 17];
    __shared__ float sv[4][64];
    const int t = threadIdx.x;
    #pragma unroll
    for (int k = 0; k < 4; ++k) {
        int idx = t + k * 256;
        Ws2[(idx >> 4) * 17 + (idx & 15)] = W2[idx];
    }
    __syncthreads();

    const int wv = t >> 6;
    const int j  = t & 63;
    const int g  = j >> 3;     // edge sub-group 0..7
    const int h  = j & 7;      // head
    const int node = blockIdx.x * 4 + wv;
    const bool active = node < n;

    if (active) {
        const int d = node;
        const int start = rowptr[d], end = rowptr[d + 1];
        const float adsth = adst1[d * 8 + h];
        float acc[8] = {};
        float dsum = 0.f;
        for (int base = start - 1; base < end; base += 8) {
            int i = base + g;
            if (i < end) {
                int s = (i < start) ? d : ssrc[i];
                float e = asrc1[s * 8 + h] + adsth;
                e = e > 0.f ? e : NEG_SLOPE * e;
                float ex = __expf(e);
                dsum += ex;
                u16x8 hv = *(const u16x8*)(h1b + (size_t)s * 64 + h * 8);
                #pragma unroll
                for (int c = 0; c < 8; ++c) acc[c] += ex * bf2f(hv[c]);
            }
        }
        // reduce across the 8 edge sub-groups (xor masks 8,16,32)
        #pragma unroll
        for (int o = 8; o < 64; o <<= 1) {
            dsum += __shfl_xor(dsum, o);
            #pragma unroll
            for (int c = 0; c < 8; ++c) acc[c] += __shfl_xor(acc[c], o);
        }
        if (g == 0) {
            float den = dsum + 1e-16f;
            #pragma unroll
            for (int c = 0; c < 8; ++c) {
                float v = acc[c] / den + b1[h * 8 + c];
                v = v > 0.f ? v : (__expf(v) - 1.f);   // ELU
                sv[wv][h * 8 + c] = v;
            }
        }
    }
    __syncthreads();

    if (active) {
        const int c = j & 15, q = j >> 4;
        float p = 0.f;
        #pragma unroll
        for (int r = 0; r < 16; ++r)
            p += sv[wv][q * 16 + r] * Ws2[(q * 16 + r) * 17 + c];
        p += __shfl_xor(p, 16);
        p += __shfl_xor(p, 32);
        if (j < 16) h2b[(size_t)node * 16 + j] = f2bf(p);
        float as2 = p * att_src2[c];
        float ad2 = p * att_dst2[c];
        #pragma unroll
        for (int o = 1; o < 16; o <<= 1) { as2 += __shfl_xor(as2, o, 16); ad2 += __shfl_xor(ad2, o, 16); }
        if (j == 0) { asrc2[node] = as2; adst2[node] = ad2; }
    }
}

// ---------------- layer2 aggregate + log_softmax ----------------
// one wave per node; 16 edges in flight (g=lane>>2), lane handles channels (lane&3)*4..+3
__global__ __launch_bounds__(256) void agg2_k(
    const int* __restrict__ rowptr, const int* __restrict__ ssrc,
    const float* __restrict__ asrc2, const float* __restrict__ adst2,
    const ushort* __restrict__ h2b, const float* __restrict__ b2,
    float* __restrict__ out, int n)
{
    const int t = threadIdx.x;
    const int node = blockIdx.x * 4 + (t >> 6);
    if (node >= n) return;
    const int j = t & 63;
    const int g = j >> 2;      // edge sub-group 0..15
    const int q = j & 3;       // channel quad
    const int d = node;
    const int start = rowptr[d], end = rowptr[d + 1];
    const float adst_d = adst2[d];

    float acc[4] = {};
    float dsum = 0.f;
    for (int base = start - 1; base < end; base += 16) {
        int i = base + g;
        if (i < end) {
            int s = (i < start) ? d : ssrc[i];
            float e = asrc2[s] + adst_d;
            e = e > 0.f ? e : NEG_SLOPE * e;
            float ex = __expf(e);
            dsum += ex;
            u16x4 hv = *(const u16x4*)(h2b + (size_t)s * 16 + q * 4);
            #pragma unroll
            for (int c = 0; c < 4; ++c) acc[c] += ex * bf2f(hv[c]);
        }
    }
    // reduce across 16 edge sub-groups (xor masks 4,8,16,32)
    #pragma unroll
    for (int o = 4; o < 64; o <<= 1) {
        dsum += __shfl_xor(dsum, o);
        #pragma unroll
        for (int c = 0; c < 4; ++c) acc[c] += __shfl_xor(acc[c], o);
    }

    const float den = dsum + 1e-16f;
    float v[4];
    float m = -1e30f;
    #pragma unroll
    for (int c = 0; c < 4; ++c) {
        v[c] = acc[c] / den + b2[q * 4 + c];
        m = fmaxf(m, v[c]);
    }
    m = fmaxf(m, __shfl_xor(m, 1));
    m = fmaxf(m, __shfl_xor(m, 2));
    float s2 = 0.f;
    #pragma unroll
    for (int c = 0; c < 4; ++c) s2 += __expf(v[c] - m);
    s2 += __shfl_xor(s2, 1);
    s2 += __shfl_xor(s2, 2);
    const float lse = m + logf(s2);
    if (j < 4) {
        float4 o4 = make_float4(v[0] - lse, v[1] - lse, v[2] - lse, v[3] - lse);
        *(float4*)(out + (size_t)d * 16 + q * 4) = o4;
    }
}

extern "C" void kernel_launch(void* const* d_in, const int* in_sizes, int n_in,
                              void* d_out, int out_size, void* d_ws, size_t ws_size,
                              hipStream_t stream) {
    const float* x        = (const float*)d_in[0];
    const int*   ei       = (const int*)d_in[1];
    const float* W1       = (const float*)d_in[2];
    const float* att_src1 = (const float*)d_in[3];
    const float* att_dst1 = (const float*)d_in[4];
    const float* b1       = (const float*)d_in[5];
    const float* W2       = (const float*)d_in[6];
    const float* att_src2 = (const float*)d_in[7];
    const float* att_dst2 = (const float*)d_in[8];
    const float* b2       = (const float*)d_in[9];
    float* out = (float*)d_out;

    const int n = in_sizes[0] / 512;
    const int E = in_sizes[1] / 2;

    char* base = (char*)d_ws;
    ushort* h1b   = (ushort*)(base);                          // 128n B
    ushort* h2b   = (ushort*)(base + (size_t)128 * n);        // 32n B
    float*  asrc1 = (float*) (base + (size_t)160 * n);        // 32n B
    float*  adst1 = (float*) (base + (size_t)192 * n);        // 32n B
    float*  asrc2 = (float*) (base + (size_t)224 * n);        // 4n B
    float*  adst2 = (float*) (base + (size_t)228 * n);        // 4n B
    int*    rowptr= (int*)   (base + (size_t)232 * n);        // 4n+4 B
    int*    cnt   = (int*)   (base + (size_t)236 * n + 4);    // 4n B
    int*    off   = (int*)   (base + (size_t)240 * n + 4);    // 4n B
    int*    ssrc  = (int*)   (base + (size_t)244 * n + 4);    // 4E B

    hipMemsetAsync(cnt, 0, (size_t)8 * n, stream);   // cnt + off

    hist_k<<<(E + 255) / 256, 256, 0, stream>>>(ei, cnt, E);
    scan_k<<<1, 1024, 0, stream>>>(cnt, rowptr, n, E);
    scatter_k<<<(E + 255) / 256, 256, 0, stream>>>(ei, rowptr, off, ssrc, E);

    gemm1_mfma<<<(n + 63) / 64, 256, 0, stream>>>(x, W1, h1b, n);
    att1_k<<<(n * 64 + 255) / 256, 256, 0, stream>>>(h1b, att_src1, att_dst1, asrc1, adst1, n);

    agg1_k<<<(n + 3) / 4, 256, 0, stream>>>(rowptr, ssrc, asrc1, adst1, h1b, b1,
                                            W2, att_src2, att_dst2, h2b, asrc2, adst2, n);

    agg2_k<<<(n + 3) / 4, 256, 0, stream>>>(rowptr, ssrc, asrc2, adst2, h2b, b2, out, n);
}

// Round 5
// 350.242 us; speedup vs baseline: 10.5814x; 1.4789x over previous
//
#include <hip/hip_runtime.h>
#include <hip/hip_bf16.h>

#define NEG_SLOPE 0.2f

typedef __attribute__((ext_vector_type(8))) short  bf16x8;
typedef __attribute__((ext_vector_type(8))) unsigned short u16x8;
typedef __attribute__((ext_vector_type(4))) unsigned short u16x4;
typedef __attribute__((ext_vector_type(4))) float  f32x4;

static __device__ __forceinline__ ushort f2bf(float f) {
    union { float f; unsigned int u; } c; c.f = f;
    unsigned int r = c.u + 0x7fffu + ((c.u >> 16) & 1u);   // round-to-nearest-even
    return (ushort)(r >> 16);
}
static __device__ __forceinline__ float bf2f(ushort u) {
    union { unsigned int u; float f; } c; c.u = ((unsigned int)u) << 16;
    return c.f;
}

// ---------------- GEMM1 via bf16 MFMA: h1b = bf16(x @ W1) ----------------
__global__ __launch_bounds__(256) void gemm1_mfma(
    const float* __restrict__ x, const float* __restrict__ W,
    ushort* __restrict__ h1b, int n)
{
    __shared__ ushort Bs[64][520];  // W1 transposed [col][k], bf16
    __shared__ ushort As[64][72];   // x tile [row][kk], bf16
    const int t    = threadIdx.x;
    const int lane = t & 63;
    const int wv   = t >> 6;
    const int rb   = blockIdx.x * 64;
    const int m    = lane & 15;
    const int kg   = lane >> 4;

    #pragma unroll 4
    for (int i = 0; i < 32; ++i) {
        int idx = (t + i * 256) * 4;
        float4 v = *(const float4*)(W + idx);
        int k = idx >> 6, c = idx & 63;
        Bs[c + 0][k] = f2bf(v.x); Bs[c + 1][k] = f2bf(v.y);
        Bs[c + 2][k] = f2bf(v.z); Bs[c + 3][k] = f2bf(v.w);
    }
    f32x4 acc[4] = {};
    __syncthreads();

    for (int kc = 0; kc < 512; kc += 64) {
        {
            int r = t >> 2, kq = (t & 3) * 16;
            int gr = rb + r;
            float4 a = {}, b = {}, c4 = {}, d4 = {};
            if (gr < n) {
                const float* p = x + (size_t)gr * 512 + kc + kq;
                a  = *(const float4*)(p);
                b  = *(const float4*)(p + 4);
                c4 = *(const float4*)(p + 8);
                d4 = *(const float4*)(p + 12);
            }
            u16x8 u0, u1;
            u0[0]=f2bf(a.x);  u0[1]=f2bf(a.y);  u0[2]=f2bf(a.z);  u0[3]=f2bf(a.w);
            u0[4]=f2bf(b.x);  u0[5]=f2bf(b.y);  u0[6]=f2bf(b.z);  u0[7]=f2bf(b.w);
            u1[0]=f2bf(c4.x); u1[1]=f2bf(c4.y); u1[2]=f2bf(c4.z); u1[3]=f2bf(c4.w);
            u1[4]=f2bf(d4.x); u1[5]=f2bf(d4.y); u1[6]=f2bf(d4.z); u1[7]=f2bf(d4.w);
            *(u16x8*)&As[r][kq]     = u0;
            *(u16x8*)&As[r][kq + 8] = u1;
        }
        __syncthreads();
        #pragma unroll
        for (int ks = 0; ks < 2; ++ks) {
            bf16x8 af = *(const bf16x8*)&As[wv * 16 + m][ks * 32 + kg * 8];
            #pragma unroll
            for (int t4 = 0; t4 < 4; ++t4) {
                bf16x8 bfr = *(const bf16x8*)&Bs[t4 * 16 + m][kc + ks * 32 + kg * 8];
                acc[t4] = __builtin_amdgcn_mfma_f32_16x16x32_bf16(af, bfr, acc[t4], 0, 0, 0);
            }
        }
        __syncthreads();
    }

    #pragma unroll
    for (int t4 = 0; t4 < 4; ++t4)
        #pragma unroll
        for (int i = 0; i < 4; ++i) {
            int gr = rb + wv * 16 + kg * 4 + i;
            if (gr < n) h1b[(size_t)gr * 64 + t4 * 16 + m] = f2bf(acc[t4][i]);
        }
}

// ---------------- att1: asrc/adst from h1b ----------------
__global__ __launch_bounds__(256) void att1_k(
    const ushort* __restrict__ h1b, const float* __restrict__ as, const float* __restrict__ ad,
    float* __restrict__ asrc, float* __restrict__ adst, int n)
{
    int idx = blockIdx.x * 256 + threadIdx.x;
    if (idx >= n * 64) return;
    int j = idx & 63;
    float v = bf2f(h1b[idx]);
    float ps = v * as[j], pd = v * ad[j];
    ps += __shfl_xor(ps, 1); pd += __shfl_xor(pd, 1);
    ps += __shfl_xor(ps, 2); pd += __shfl_xor(pd, 2);
    ps += __shfl_xor(ps, 4); pd += __shfl_xor(pd, 4);
    if ((j & 7) == 0) {
        int node = idx >> 6;
        asrc[node * 8 + (j >> 3)] = ps;
        adst[node * 8 + (j >> 3)] = pd;
    }
}

// ---------------- CSR build ----------------
__global__ __launch_bounds__(256) void hist_k(const int* __restrict__ ei, int* __restrict__ cnt, int E)
{
    int t = blockIdx.x * blockDim.x + threadIdx.x;
    if (t < E) atomicAdd(&cnt[ei[E + t]], 1);
}

#define SCAN_B 256
#define SCAN_T 256

// per-block sums of cnt chunks
__global__ __launch_bounds__(SCAN_T) void scan_a(const int* __restrict__ cnt, int* __restrict__ bsum, int n)
{
    __shared__ int sh[SCAN_T];
    const int tid = threadIdx.x;
    const int per = (n + SCAN_B * SCAN_T - 1) / (SCAN_B * SCAN_T);
    const int lo = (blockIdx.x * SCAN_T + tid) * per;
    const int hi = min(n, lo + per);
    int s = 0;
    for (int i = lo; i < hi; ++i) s += cnt[i];
    sh[tid] = s;
    __syncthreads();
    #pragma unroll
    for (int o = SCAN_T / 2; o; o >>= 1) {
        if (tid < o) sh[tid] += sh[tid + o];
        __syncthreads();
    }
    if (tid == 0) bsum[blockIdx.x] = sh[0];
}

// every block: scan bsum in LDS for its offset, rescan its chunk, emit rowptr
__global__ __launch_bounds__(SCAN_T) void scan_b(
    const int* __restrict__ cnt, const int* __restrict__ bsum,
    int* __restrict__ rowptr, int n, int E)
{
    __shared__ int sb[SCAN_B];
    __shared__ int sh[SCAN_T];
    const int tid = threadIdx.x;
    sb[tid] = bsum[tid];
    __syncthreads();
    #pragma unroll
    for (int o = 1; o < SCAN_B; o <<= 1) {
        int v = (tid >= o) ? sb[tid - o] : 0;
        __syncthreads();
        sb[tid] += v;
        __syncthreads();
    }
    const int boff = (blockIdx.x == 0) ? 0 : sb[blockIdx.x - 1];

    const int per = (n + SCAN_B * SCAN_T - 1) / (SCAN_B * SCAN_T);
    const int lo = (blockIdx.x * SCAN_T + tid) * per;
    const int hi = min(n, lo + per);
    int s = 0;
    for (int i = lo; i < hi; ++i) s += cnt[i];
    sh[tid] = s;
    __syncthreads();
    #pragma unroll
    for (int o = 1; o < SCAN_T; o <<= 1) {
        int v = (tid >= o) ? sh[tid - o] : 0;
        __syncthreads();
        sh[tid] += v;
        __syncthreads();
    }
    int excl = boff + ((tid == 0) ? 0 : sh[tid - 1]);
    for (int i = lo; i < hi; ++i) { rowptr[i] = excl; excl += cnt[i]; }
    if (blockIdx.x == 0 && tid == 0) rowptr[n] = E;
}

__global__ __launch_bounds__(256) void scatter_k(
    const int* __restrict__ ei, const int* __restrict__ rowptr,
    int* __restrict__ off, int* __restrict__ ssrc, int E)
{
    int t = blockIdx.x * blockDim.x + threadIdx.x;
    if (t >= E) return;
    int d = ei[E + t];
    int p = rowptr[d] + atomicAdd(&off[d], 1);
    ssrc[p] = ei[t];
}

// ---------------- layer1 aggregate + ELU + GEMM2 + att2 ----------------
__global__ __launch_bounds__(256) void agg1_k(
    const int* __restrict__ rowptr, const int* __restrict__ ssrc,
    const float* __restrict__ asrc1, const float* __restrict__ adst1,
    const ushort* __restrict__ h1b, const float* __restrict__ b1,
    const float* __restrict__ W2, const float* __restrict__ att_src2, const float* __restrict__ att_dst2,
    ushort* __restrict__ h2b, float* __restrict__ asrc2, float* __restrict__ adst2, int n)
{
    __shared__ float Ws2[64 * 17];
    __shared__ float sv[4][64];
    const int t = threadIdx.x;
    #pragma unroll
    for (int k = 0; k < 4; ++k) {
        int idx = t + k * 256;
        Ws2[(idx >> 4) * 17 + (idx & 15)] = W2[idx];
    }
    __syncthreads();

    const int wv = t >> 6;
    const int j  = t & 63;
    const int g  = j >> 3;     // edge sub-group 0..7
    const int h  = j & 7;      // head
    const int node = blockIdx.x * 4 + wv;
    const bool active = node < n;

    if (active) {
        const int d = node;
        const int start = rowptr[d], end = rowptr[d + 1];
        const float adsth = adst1[d * 8 + h];
        float acc[8] = {};
        float dsum = 0.f;
        for (int base = start - 1; base < end; base += 8) {
            int i = base + g;
            if (i < end) {
                int s = (i < start) ? d : ssrc[i];
                float e = asrc1[s * 8 + h] + adsth;
                e = e > 0.f ? e : NEG_SLOPE * e;
                float ex = __expf(e);
                dsum += ex;
                u16x8 hv = *(const u16x8*)(h1b + (size_t)s * 64 + h * 8);
                #pragma unroll
                for (int c = 0; c < 8; ++c) acc[c] += ex * bf2f(hv[c]);
            }
        }
        #pragma unroll
        for (int o = 8; o < 64; o <<= 1) {
            dsum += __shfl_xor(dsum, o);
            #pragma unroll
            for (int c = 0; c < 8; ++c) acc[c] += __shfl_xor(acc[c], o);
        }
        if (g == 0) {
            float den = dsum + 1e-16f;
            #pragma unroll
            for (int c = 0; c < 8; ++c) {
                float v = acc[c] / den + b1[h * 8 + c];
                v = v > 0.f ? v : (__expf(v) - 1.f);   // ELU
                sv[wv][h * 8 + c] = v;
            }
        }
    }
    __syncthreads();

    if (active) {
        const int c = j & 15, q = j >> 4;
        float p = 0.f;
        #pragma unroll
        for (int r = 0; r < 16; ++r)
            p += sv[wv][q * 16 + r] * Ws2[(q * 16 + r) * 17 + c];
        p += __shfl_xor(p, 16);
        p += __shfl_xor(p, 32);
        if (j < 16) h2b[(size_t)node * 16 + j] = f2bf(p);
        float as2 = p * att_src2[c];
        float ad2 = p * att_dst2[c];
        #pragma unroll
        for (int o = 1; o < 16; o <<= 1) { as2 += __shfl_xor(as2, o, 16); ad2 += __shfl_xor(ad2, o, 16); }
        if (j == 0) { asrc2[node] = as2; adst2[node] = ad2; }
    }
}

// ---------------- layer2 aggregate + log_softmax ----------------
__global__ __launch_bounds__(256) void agg2_k(
    const int* __restrict__ rowptr, const int* __restrict__ ssrc,
    const float* __restrict__ asrc2, const float* __restrict__ adst2,
    const ushort* __restrict__ h2b, const float* __restrict__ b2,
    float* __restrict__ out, int n)
{
    const int t = threadIdx.x;
    const int node = blockIdx.x * 4 + (t >> 6);
    if (node >= n) return;
    const int j = t & 63;
    const int g = j >> 2;      // edge sub-group 0..15
    const int q = j & 3;       // channel quad
    const int d = node;
    const int start = rowptr[d], end = rowptr[d + 1];
    const float adst_d = adst2[d];

    float acc[4] = {};
    float dsum = 0.f;
    for (int base = start - 1; base < end; base += 16) {
        int i = base + g;
        if (i < end) {
            int s = (i < start) ? d : ssrc[i];
            float e = asrc2[s] + adst_d;
            e = e > 0.f ? e : NEG_SLOPE * e;
            float ex = __expf(e);
            dsum += ex;
            u16x4 hv = *(const u16x4*)(h2b + (size_t)s * 16 + q * 4);
            #pragma unroll
            for (int c = 0; c < 4; ++c) acc[c] += ex * bf2f(hv[c]);
        }
    }
    #pragma unroll
    for (int o = 4; o < 64; o <<= 1) {
        dsum += __shfl_xor(dsum, o);
        #pragma unroll
        for (int c = 0; c < 4; ++c) acc[c] += __shfl_xor(acc[c], o);
    }

    const float den = dsum + 1e-16f;
    float v[4];
    float m = -1e30f;
    #pragma unroll
    for (int c = 0; c < 4; ++c) {
        v[c] = acc[c] / den + b2[q * 4 + c];
        m = fmaxf(m, v[c]);
    }
    m = fmaxf(m, __shfl_xor(m, 1));
    m = fmaxf(m, __shfl_xor(m, 2));
    float s2 = 0.f;
    #pragma unroll
    for (int c = 0; c < 4; ++c) s2 += __expf(v[c] - m);
    s2 += __shfl_xor(s2, 1);
    s2 += __shfl_xor(s2, 2);
    const float lse = m + logf(s2);
    if (j < 4) {
        float4 o4 = make_float4(v[0] - lse, v[1] - lse, v[2] - lse, v[3] - lse);
        *(float4*)(out + (size_t)d * 16 + q * 4) = o4;
    }
}

extern "C" void kernel_launch(void* const* d_in, const int* in_sizes, int n_in,
                              void* d_out, int out_size, void* d_ws, size_t ws_size,
                              hipStream_t stream) {
    const float* x        = (const float*)d_in[0];
    const int*   ei       = (const int*)d_in[1];
    const float* W1       = (const float*)d_in[2];
    const float* att_src1 = (const float*)d_in[3];
    const float* att_dst1 = (const float*)d_in[4];
    const float* b1       = (const float*)d_in[5];
    const float* W2       = (const float*)d_in[6];
    const float* att_src2 = (const float*)d_in[7];
    const float* att_dst2 = (const float*)d_in[8];
    const float* b2       = (const float*)d_in[9];
    float* out = (float*)d_out;

    const int n = in_sizes[0] / 512;
    const int E = in_sizes[1] / 2;

    char* base = (char*)d_ws;
    ushort* h1b   = (ushort*)(base);                          // 128n B
    ushort* h2b   = (ushort*)(base + (size_t)128 * n);        // 32n B
    float*  asrc1 = (float*) (base + (size_t)160 * n);        // 32n B
    float*  adst1 = (float*) (base + (size_t)192 * n);        // 32n B
    float*  asrc2 = (float*) (base + (size_t)224 * n);        // 4n B
    float*  adst2 = (float*) (base + (size_t)228 * n);        // 4n B
    int*    rowptr= (int*)   (base + (size_t)232 * n);        // 4n+4 B
    int*    cnt   = (int*)   (base + (size_t)236 * n + 4);    // 4n B
    int*    off   = (int*)   (base + (size_t)240 * n + 4);    // 4n B
    int*    bsum  = (int*)   (base + (size_t)244 * n + 4);    // 1024 B
    int*    ssrc  = (int*)   (base + (size_t)244 * n + 4 + 1024); // 4E B

    hipMemsetAsync(cnt, 0, (size_t)8 * n, stream);   // cnt + off

    hist_k<<<(E + 255) / 256, 256, 0, stream>>>(ei, cnt, E);
    scan_a<<<SCAN_B, SCAN_T, 0, stream>>>(cnt, bsum, n);
    scan_b<<<SCAN_B, SCAN_T, 0, stream>>>(cnt, bsum, rowptr, n, E);
    scatter_k<<<(E + 255) / 256, 256, 0, stream>>>(ei, rowptr, off, ssrc, E);

    gemm1_mfma<<<(n + 63) / 64, 256, 0, stream>>>(x, W1, h1b, n);
    att1_k<<<(n * 64 + 255) / 256, 256, 0, stream>>>(h1b, att_src1, att_dst1, asrc1, adst1, n);

    agg1_k<<<(n + 3) / 4, 256, 0, stream>>>(rowptr, ssrc, asrc1, adst1, h1b, b1,
                                            W2, att_src2, att_dst2, h2b, asrc2, adst2, n);

    agg2_k<<<(n + 3) / 4, 256, 0, stream>>>(rowptr, ssrc, asrc2, adst2, h2b, b2, out, n);
}

// Round 6
// 332.187 us; speedup vs baseline: 11.1565x; 1.0544x over previous
//
#include <hip/hip_runtime.h>
#include <hip/hip_bf16.h>

#define NEG_SLOPE 0.2f

typedef __attribute__((ext_vector_type(8))) short  bf16x8;
typedef __attribute__((ext_vector_type(8))) unsigned short u16x8;
typedef __attribute__((ext_vector_type(4))) unsigned short u16x4;
typedef __attribute__((ext_vector_type(4))) float  f32x4;

static __device__ __forceinline__ ushort f2bf(float f) {
    union { float f; unsigned int u; } c; c.f = f;
    unsigned int r = c.u + 0x7fffu + ((c.u >> 16) & 1u);   // round-to-nearest-even
    return (ushort)(r >> 16);
}
static __device__ __forceinline__ float bf2f(ushort u) {
    union { unsigned int u; float f; } c; c.u = ((unsigned int)u) << 16;
    return c.f;
}

// ---------------- GEMM1 via bf16 MFMA, barrier-free K loop, fused att1 ----------------
// h1b = bf16(x @ W1); asrc/adst = per-head reductions of f32 accumulators
__global__ __launch_bounds__(256) void gemm1_mfma(
    const float* __restrict__ x, const float* __restrict__ W,
    const float* __restrict__ att_src, const float* __restrict__ att_dst,
    ushort* __restrict__ h1b, float* __restrict__ asrc, float* __restrict__ adst, int n)
{
    __shared__ ushort Bs[64][520];  // W1 transposed [col][k], bf16 (16B-aligned rows)
    const int t    = threadIdx.x;
    const int lane = t & 63;
    const int wv   = t >> 6;
    const int rb   = blockIdx.x * 64;
    const int m    = lane & 15;
    const int kg   = lane >> 4;

    // stage all of W1 (512x64 f32) -> Bs[col][k] bf16 (once per block)
    #pragma unroll 4
    for (int i = 0; i < 32; ++i) {
        int idx = (t + i * 256) * 4;
        float4 v = *(const float4*)(W + idx);
        int k = idx >> 6, c = idx & 63;
        Bs[c + 0][k] = f2bf(v.x); Bs[c + 1][k] = f2bf(v.y);
        Bs[c + 2][k] = f2bf(v.z); Bs[c + 3][k] = f2bf(v.w);
    }

    // A operand: row = lane&15 within the wave's 16-row strip
    const int arow  = rb + wv * 16 + m;
    const int arowc = min(arow, n - 1);                  // clamp OOB rows (results discarded)
    const float* xp = x + (size_t)arowc * 512 + kg * 8;

    f32x4 acc[4] = {};
    __syncthreads();

    // barrier-free: 16 steps of K=32, A direct from global, B from LDS
    #pragma unroll 4
    for (int k32 = 0; k32 < 16; ++k32) {
        float4 lo = *(const float4*)(xp + k32 * 32);
        float4 hi = *(const float4*)(xp + k32 * 32 + 4);
        u16x8 a;
        a[0] = f2bf(lo.x); a[1] = f2bf(lo.y); a[2] = f2bf(lo.z); a[3] = f2bf(lo.w);
        a[4] = f2bf(hi.x); a[5] = f2bf(hi.y); a[6] = f2bf(hi.z); a[7] = f2bf(hi.w);
        bf16x8 af = *(bf16x8*)&a;
        #pragma unroll
        for (int t4 = 0; t4 < 4; ++t4) {
            bf16x8 bfr = *(const bf16x8*)&Bs[t4 * 16 + m][k32 * 32 + kg * 8];
            acc[t4] = __builtin_amdgcn_mfma_f32_16x16x32_bf16(af, bfr, acc[t4], 0, 0, 0);
        }
    }

    // epilogue: C/D layout col=lane&15(=m), row=kg*4+i. Store h1b + fused per-head att sums.
    #pragma unroll
    for (int t4 = 0; t4 < 4; ++t4) {
        const float as_w = att_src[t4 * 16 + m];
        const float ad_w = att_dst[t4 * 16 + m];
        #pragma unroll
        for (int i = 0; i < 4; ++i) {
            int gr = rb + wv * 16 + kg * 4 + i;
            float v = acc[t4][i];
            float ps = v * as_w, pd = v * ad_w;
            ps += __shfl_xor(ps, 1); pd += __shfl_xor(pd, 1);
            ps += __shfl_xor(ps, 2); pd += __shfl_xor(pd, 2);
            ps += __shfl_xor(ps, 4); pd += __shfl_xor(pd, 4);
            if (gr < n) {
                h1b[(size_t)gr * 64 + t4 * 16 + m] = f2bf(v);
                if ((m & 7) == 0) {
                    int h = t4 * 2 + (m >> 3);
                    asrc[gr * 8 + h] = ps;
                    adst[gr * 8 + h] = pd;
                }
            }
        }
    }
}

// ---------------- CSR build ----------------
__global__ __launch_bounds__(256) void hist_k(const int* __restrict__ ei, int* __restrict__ cnt, int E)
{
    int t = blockIdx.x * blockDim.x + threadIdx.x;
    if (t < E) atomicAdd(&cnt[ei[E + t]], 1);
}

#define SCAN_B 256
#define SCAN_T 256

__global__ __launch_bounds__(SCAN_T) void scan_a(const int* __restrict__ cnt, int* __restrict__ bsum, int n)
{
    __shared__ int sh[SCAN_T];
    const int tid = threadIdx.x;
    const int per = (n + SCAN_B * SCAN_T - 1) / (SCAN_B * SCAN_T);
    const int lo = (blockIdx.x * SCAN_T + tid) * per;
    const int hi = min(n, lo + per);
    int s = 0;
    for (int i = lo; i < hi; ++i) s += cnt[i];
    sh[tid] = s;
    __syncthreads();
    #pragma unroll
    for (int o = SCAN_T / 2; o; o >>= 1) {
        if (tid < o) sh[tid] += sh[tid + o];
        __syncthreads();
    }
    if (tid == 0) bsum[blockIdx.x] = sh[0];
}

__global__ __launch_bounds__(SCAN_T) void scan_b(
    const int* __restrict__ cnt, const int* __restrict__ bsum,
    int* __restrict__ rowptr, int n, int E)
{
    __shared__ int sb[SCAN_B];
    __shared__ int sh[SCAN_T];
    const int tid = threadIdx.x;
    sb[tid] = bsum[tid];
    __syncthreads();
    #pragma unroll
    for (int o = 1; o < SCAN_B; o <<= 1) {
        int v = (tid >= o) ? sb[tid - o] : 0;
        __syncthreads();
        sb[tid] += v;
        __syncthreads();
    }
    const int boff = (blockIdx.x == 0) ? 0 : sb[blockIdx.x - 1];

    const int per = (n + SCAN_B * SCAN_T - 1) / (SCAN_B * SCAN_T);
    const int lo = (blockIdx.x * SCAN_T + tid) * per;
    const int hi = min(n, lo + per);
    int s = 0;
    for (int i = lo; i < hi; ++i) s += cnt[i];
    sh[tid] = s;
    __syncthreads();
    #pragma unroll
    for (int o = 1; o < SCAN_T; o <<= 1) {
        int v = (tid >= o) ? sh[tid - o] : 0;
        __syncthreads();
        sh[tid] += v;
        __syncthreads();
    }
    int excl = boff + ((tid == 0) ? 0 : sh[tid - 1]);
    for (int i = lo; i < hi; ++i) { rowptr[i] = excl; excl += cnt[i]; }
    if (blockIdx.x == 0 && tid == 0) rowptr[n] = E;
}

__global__ __launch_bounds__(256) void scatter_k(
    const int* __restrict__ ei, const int* __restrict__ rowptr,
    int* __restrict__ off, int* __restrict__ ssrc, int E)
{
    int t = blockIdx.x * blockDim.x + threadIdx.x;
    if (t >= E) return;
    int d = ei[E + t];
    int p = rowptr[d] + atomicAdd(&off[d], 1);
    ssrc[p] = ei[t];
}

// ---------------- layer1 aggregate + ELU + GEMM2 + att2 ----------------
// one wave per node; 16 edges in flight (2-way unroll of 8 g-groups), lane = g*8+h
__global__ __launch_bounds__(256) void agg1_k(
    const int* __restrict__ rowptr, const int* __restrict__ ssrc,
    const float* __restrict__ asrc1, const float* __restrict__ adst1,
    const ushort* __restrict__ h1b, const float* __restrict__ b1,
    const float* __restrict__ W2, const float* __restrict__ att_src2, const float* __restrict__ att_dst2,
    ushort* __restrict__ h2b, float* __restrict__ asrc2, float* __restrict__ adst2, int n)
{
    __shared__ float Ws2[64 * 17];
    __shared__ float sv[4][64];
    const int t = threadIdx.x;
    #pragma unroll
    for (int k = 0; k < 4; ++k) {
        int idx = t + k * 256;
        Ws2[(idx >> 4) * 17 + (idx & 15)] = W2[idx];
    }
    __syncthreads();

    const int wv = t >> 6;
    const int j  = t & 63;
    const int g  = j >> 3;     // edge sub-group 0..7
    const int h  = j & 7;      // head
    const int node = blockIdx.x * 4 + wv;
    const bool active = node < n;

    if (active) {
        const int d = node;
        const int start = rowptr[d], end = rowptr[d + 1];
        const float adsth = adst1[d * 8 + h];
        float acc0[8] = {}, acc1[8] = {};
        float dsum0 = 0.f, dsum1 = 0.f;
        for (int base = start - 1; base < end; base += 16) {
            int i0 = base + g;
            int i1 = i0 + 8;
            if (i0 < end) {
                int s = (i0 < start) ? d : ssrc[i0];
                float e = asrc1[s * 8 + h] + adsth;
                e = e > 0.f ? e : NEG_SLOPE * e;
                float ex = __expf(e);
                dsum0 += ex;
                u16x8 hv = *(const u16x8*)(h1b + (size_t)s * 64 + h * 8);
                #pragma unroll
                for (int c = 0; c < 8; ++c) acc0[c] += ex * bf2f(hv[c]);
            }
            if (i1 < end) {
                int s = ssrc[i1];                      // i1 >= start always
                float e = asrc1[s * 8 + h] + adsth;
                e = e > 0.f ? e : NEG_SLOPE * e;
                float ex = __expf(e);
                dsum1 += ex;
                u16x8 hv = *(const u16x8*)(h1b + (size_t)s * 64 + h * 8);
                #pragma unroll
                for (int c = 0; c < 8; ++c) acc1[c] += ex * bf2f(hv[c]);
            }
        }
        float dsum = dsum0 + dsum1;
        float acc[8];
        #pragma unroll
        for (int c = 0; c < 8; ++c) acc[c] = acc0[c] + acc1[c];
        #pragma unroll
        for (int o = 8; o < 64; o <<= 1) {
            dsum += __shfl_xor(dsum, o);
            #pragma unroll
            for (int c = 0; c < 8; ++c) acc[c] += __shfl_xor(acc[c], o);
        }
        if (g == 0) {
            float den = dsum + 1e-16f;
            #pragma unroll
            for (int c = 0; c < 8; ++c) {
                float v = acc[c] / den + b1[h * 8 + c];
                v = v > 0.f ? v : (__expf(v) - 1.f);   // ELU
                sv[wv][h * 8 + c] = v;
            }
        }
    }
    __syncthreads();

    if (active) {
        const int c = j & 15, q = j >> 4;
        float p = 0.f;
        #pragma unroll
        for (int r = 0; r < 16; ++r)
            p += sv[wv][q * 16 + r] * Ws2[(q * 16 + r) * 17 + c];
        p += __shfl_xor(p, 16);
        p += __shfl_xor(p, 32);
        if (j < 16) h2b[(size_t)node * 16 + j] = f2bf(p);
        float as2 = p * att_src2[c];
        float ad2 = p * att_dst2[c];
        #pragma unroll
        for (int o = 1; o < 16; o <<= 1) { as2 += __shfl_xor(as2, o, 16); ad2 += __shfl_xor(ad2, o, 16); }
        if (j == 0) { asrc2[node] = as2; adst2[node] = ad2; }
    }
}

// ---------------- layer2 aggregate + log_softmax ----------------
// one wave per node; 32 edges in flight (2-way unroll of 16 g-groups)
__global__ __launch_bounds__(256) void agg2_k(
    const int* __restrict__ rowptr, const int* __restrict__ ssrc,
    const float* __restrict__ asrc2, const float* __restrict__ adst2,
    const ushort* __restrict__ h2b, const float* __restrict__ b2,
    float* __restrict__ out, int n)
{
    const int t = threadIdx.x;
    const int node = blockIdx.x * 4 + (t >> 6);
    if (node >= n) return;
    const int j = t & 63;
    const int g = j >> 2;      // edge sub-group 0..15
    const int q = j & 3;       // channel quad
    const int d = node;
    const int start = rowptr[d], end = rowptr[d + 1];
    const float adst_d = adst2[d];

    float acc0[4] = {}, acc1[4] = {};
    float dsum0 = 0.f, dsum1 = 0.f;
    for (int base = start - 1; base < end; base += 32) {
        int i0 = base + g;
        int i1 = i0 + 16;
        if (i0 < end) {
            int s = (i0 < start) ? d : ssrc[i0];
            float e = asrc2[s] + adst_d;
            e = e > 0.f ? e : NEG_SLOPE * e;
            float ex = __expf(e);
            dsum0 += ex;
            u16x4 hv = *(const u16x4*)(h2b + (size_t)s * 16 + q * 4);
            #pragma unroll
            for (int c = 0; c < 4; ++c) acc0[c] += ex * bf2f(hv[c]);
        }
        if (i1 < end) {
            int s = ssrc[i1];                          // i1 >= start always
            float e = asrc2[s] + adst_d;
            e = e > 0.f ? e : NEG_SLOPE * e;
            float ex = __expf(e);
            dsum1 += ex;
            u16x4 hv = *(const u16x4*)(h2b + (size_t)s * 16 + q * 4);
            #pragma unroll
            for (int c = 0; c < 4; ++c) acc1[c] += ex * bf2f(hv[c]);
        }
    }
    float dsum = dsum0 + dsum1;
    float acc[4];
    #pragma unroll
    for (int c = 0; c < 4; ++c) acc[c] = acc0[c] + acc1[c];
    #pragma unroll
    for (int o = 4; o < 64; o <<= 1) {
        dsum += __shfl_xor(dsum, o);
        #pragma unroll
        for (int c = 0; c < 4; ++c) acc[c] += __shfl_xor(acc[c], o);
    }

    const float den = dsum + 1e-16f;
    float v[4];
    float m = -1e30f;
    #pragma unroll
    for (int c = 0; c < 4; ++c) {
        v[c] = acc[c] / den + b2[q * 4 + c];
        m = fmaxf(m, v[c]);
    }
    m = fmaxf(m, __shfl_xor(m, 1));
    m = fmaxf(m, __shfl_xor(m, 2));
    float s2 = 0.f;
    #pragma unroll
    for (int c = 0; c < 4; ++c) s2 += __expf(v[c] - m);
    s2 += __shfl_xor(s2, 1);
    s2 += __shfl_xor(s2, 2);
    const float lse = m + logf(s2);
    if (j < 4) {
        float4 o4 = make_float4(v[0] - lse, v[1] - lse, v[2] - lse, v[3] - lse);
        *(float4*)(out + (size_t)d * 16 + q * 4) = o4;
    }
}

extern "C" void kernel_launch(void* const* d_in, const int* in_sizes, int n_in,
                              void* d_out, int out_size, void* d_ws, size_t ws_size,
                              hipStream_t stream) {
    const float* x        = (const float*)d_in[0];
    const int*   ei       = (const int*)d_in[1];
    const float* W1       = (const float*)d_in[2];
    const float* att_src1 = (const float*)d_in[3];
    const float* att_dst1 = (const float*)d_in[4];
    const float* b1       = (const float*)d_in[5];
    const float* W2       = (const float*)d_in[6];
    const float* att_src2 = (const float*)d_in[7];
    const float* att_dst2 = (const float*)d_in[8];
    const float* b2       = (const float*)d_in[9];
    float* out = (float*)d_out;

    const int n = in_sizes[0] / 512;
    const int E = in_sizes[1] / 2;

    char* base = (char*)d_ws;
    ushort* h1b   = (ushort*)(base);                          // 128n B
    ushort* h2b   = (ushort*)(base + (size_t)128 * n);        // 32n B
    float*  asrc1 = (float*) (base + (size_t)160 * n);        // 32n B
    float*  adst1 = (float*) (base + (size_t)192 * n);        // 32n B
    float*  asrc2 = (float*) (base + (size_t)224 * n);        // 4n B
    float*  adst2 = (float*) (base + (size_t)228 * n);        // 4n B
    int*    rowptr= (int*)   (base + (size_t)232 * n);        // 4n+4 B
    int*    cnt   = (int*)   (base + (size_t)236 * n + 4);    // 4n B
    int*    off   = (int*)   (base + (size_t)240 * n + 4);    // 4n B
    int*    bsum  = (int*)   (base + (size_t)244 * n + 4);    // 1024 B
    int*    ssrc  = (int*)   (base + (size_t)244 * n + 4 + 1024); // 4E B

    hipMemsetAsync(cnt, 0, (size_t)8 * n, stream);   // cnt + off

    hist_k<<<(E + 255) / 256, 256, 0, stream>>>(ei, cnt, E);
    scan_a<<<SCAN_B, SCAN_T, 0, stream>>>(cnt, bsum, n);
    scan_b<<<SCAN_B, SCAN_T, 0, stream>>>(cnt, bsum, rowptr, n, E);
    scatter_k<<<(E + 255) / 256, 256, 0, stream>>>(ei, rowptr, off, ssrc, E);

    gemm1_mfma<<<(n + 63) / 64, 256, 0, stream>>>(x, W1, att_src1, att_dst1, h1b, asrc1, adst1, n);

    agg1_k<<<(n + 3) / 4, 256, 0, stream>>>(rowptr, ssrc, asrc1, adst1, h1b, b1,
                                            W2, att_src2, att_dst2, h2b, asrc2, adst2, n);

    agg2_k<<<(n + 3) / 4, 256, 0, stream>>>(rowptr, ssrc, asrc2, adst2, h2b, b2, out, n);
}

// Round 7
// 300.157 us; speedup vs baseline: 12.3470x; 1.1067x over previous
//
#include <hip/hip_runtime.h>
#include <hip/hip_bf16.h>

#define NEG_SLOPE 0.2f

typedef __attribute__((ext_vector_type(8))) short  bf16x8;
typedef __attribute__((ext_vector_type(8))) unsigned short u16x8;
typedef __attribute__((ext_vector_type(4))) unsigned short u16x4;
typedef __attribute__((ext_vector_type(4))) float  f32x4;

static __device__ __forceinline__ ushort f2bf(float f) {
    union { float f; unsigned int u; } c; c.f = f;
    unsigned int r = c.u + 0x7fffu + ((c.u >> 16) & 1u);   // round-to-nearest-even
    return (ushort)(r >> 16);
}
static __device__ __forceinline__ float bf2f(ushort u) {
    union { unsigned int u; float f; } c; c.u = ((unsigned int)u) << 16;
    return c.f;
}

// ---------------- GEMM1 via bf16 MFMA, barrier-free K loop, fused att1 ----------------
__global__ __launch_bounds__(256) void gemm1_mfma(
    const float* __restrict__ x, const float* __restrict__ W,
    const float* __restrict__ att_src, const float* __restrict__ att_dst,
    ushort* __restrict__ h1b, float* __restrict__ asrc, float* __restrict__ adst, int n)
{
    __shared__ ushort Bs[64][520];  // W1 transposed [col][k], bf16 (padded: 1040B row stride)
    const int t    = threadIdx.x;
    const int lane = t & 63;
    const int wv   = t >> 6;
    const int rb   = blockIdx.x * 64;
    const int m    = lane & 15;
    const int kg   = lane >> 4;

    // stage all of W1 (512x64 f32) -> Bs[col][k] bf16 (once per block)
    #pragma unroll 4
    for (int i = 0; i < 32; ++i) {
        int idx = (t + i * 256) * 4;
        float4 v = *(const float4*)(W + idx);
        int k = idx >> 6, c = idx & 63;
        Bs[c + 0][k] = f2bf(v.x); Bs[c + 1][k] = f2bf(v.y);
        Bs[c + 2][k] = f2bf(v.z); Bs[c + 3][k] = f2bf(v.w);
    }

    const int arow  = rb + wv * 16 + m;
    const int arowc = min(arow, n - 1);
    const float* xp = x + (size_t)arowc * 512 + kg * 8;

    f32x4 acc[4] = {};
    __syncthreads();

    // barrier-free: 16 steps of K=32, A direct from global (coalesced 128B/row), B from LDS
    #pragma unroll 8
    for (int k32 = 0; k32 < 16; ++k32) {
        float4 lo = *(const float4*)(xp + k32 * 32);
        float4 hi = *(const float4*)(xp + k32 * 32 + 4);
        u16x8 a;
        a[0] = f2bf(lo.x); a[1] = f2bf(lo.y); a[2] = f2bf(lo.z); a[3] = f2bf(lo.w);
        a[4] = f2bf(hi.x); a[5] = f2bf(hi.y); a[6] = f2bf(hi.z); a[7] = f2bf(hi.w);
        bf16x8 af = *(bf16x8*)&a;
        #pragma unroll
        for (int t4 = 0; t4 < 4; ++t4) {
            bf16x8 bfr = *(const bf16x8*)&Bs[t4 * 16 + m][k32 * 32 + kg * 8];
            acc[t4] = __builtin_amdgcn_mfma_f32_16x16x32_bf16(af, bfr, acc[t4], 0, 0, 0);
        }
    }

    // epilogue: C/D layout col=m, row=kg*4+i. Store h1b + fused per-head att sums.
    #pragma unroll
    for (int t4 = 0; t4 < 4; ++t4) {
        const float as_w = att_src[t4 * 16 + m];
        const float ad_w = att_dst[t4 * 16 + m];
        #pragma unroll
        for (int i = 0; i < 4; ++i) {
            int gr = rb + wv * 16 + kg * 4 + i;
            float v = acc[t4][i];
            float ps = v * as_w, pd = v * ad_w;
            ps += __shfl_xor(ps, 1); pd += __shfl_xor(pd, 1);
            ps += __shfl_xor(ps, 2); pd += __shfl_xor(pd, 2);
            ps += __shfl_xor(ps, 4); pd += __shfl_xor(pd, 4);
            if (gr < n) {
                h1b[(size_t)gr * 64 + t4 * 16 + m] = f2bf(v);
                if ((m & 7) == 0) {
                    int h = t4 * 2 + (m >> 3);
                    asrc[gr * 8 + h] = ps;
                    adst[gr * 8 + h] = pd;
                }
            }
        }
    }
}

// ---------------- CSR build: histogram also records each edge's slot ----------------
__global__ __launch_bounds__(256) void hist_k(
    const int* __restrict__ ei, int* __restrict__ cnt, int* __restrict__ slot, int E)
{
    int t = blockIdx.x * blockDim.x + threadIdx.x;
    if (t < E) slot[t] = atomicAdd(&cnt[ei[E + t]], 1);
}

#define SCAN_B 256
#define SCAN_T 256

__global__ __launch_bounds__(SCAN_T) void scan_a(const int* __restrict__ cnt, int* __restrict__ bsum, int n)
{
    __shared__ int sh[SCAN_T];
    const int tid = threadIdx.x;
    const int per = (n + SCAN_B * SCAN_T - 1) / (SCAN_B * SCAN_T);
    const int lo = (blockIdx.x * SCAN_T + tid) * per;
    const int hi = min(n, lo + per);
    int s = 0;
    for (int i = lo; i < hi; ++i) s += cnt[i];
    sh[tid] = s;
    __syncthreads();
    #pragma unroll
    for (int o = SCAN_T / 2; o; o >>= 1) {
        if (tid < o) sh[tid] += sh[tid + o];
        __syncthreads();
    }
    if (tid == 0) bsum[blockIdx.x] = sh[0];
}

__global__ __launch_bounds__(SCAN_T) void scan_b(
    const int* __restrict__ cnt, const int* __restrict__ bsum,
    int* __restrict__ rowptr, int n, int E)
{
    __shared__ int sb[SCAN_B];
    __shared__ int sh[SCAN_T];
    const int tid = threadIdx.x;
    sb[tid] = bsum[tid];
    __syncthreads();
    #pragma unroll
    for (int o = 1; o < SCAN_B; o <<= 1) {
        int v = (tid >= o) ? sb[tid - o] : 0;
        __syncthreads();
        sb[tid] += v;
        __syncthreads();
    }
    const int boff = (blockIdx.x == 0) ? 0 : sb[blockIdx.x - 1];

    const int per = (n + SCAN_B * SCAN_T - 1) / (SCAN_B * SCAN_T);
    const int lo = (blockIdx.x * SCAN_T + tid) * per;
    const int hi = min(n, lo + per);
    int s = 0;
    for (int i = lo; i < hi; ++i) s += cnt[i];
    sh[tid] = s;
    __syncthreads();
    #pragma unroll
    for (int o = 1; o < SCAN_T; o <<= 1) {
        int v = (tid >= o) ? sh[tid - o] : 0;
        __syncthreads();
        sh[tid] += v;
        __syncthreads();
    }
    int excl = boff + ((tid == 0) ? 0 : sh[tid - 1]);
    for (int i = lo; i < hi; ++i) { rowptr[i] = excl; excl += cnt[i]; }
    if (blockIdx.x == 0 && tid == 0) rowptr[n] = E;
}

// atomic-free scatter: position = rowptr[d] + slot[e]
__global__ __launch_bounds__(256) void scatter_k(
    const int* __restrict__ ei, const int* __restrict__ rowptr,
    const int* __restrict__ slot, int* __restrict__ ssrc, int E)
{
    int t = blockIdx.x * blockDim.x + threadIdx.x;
    if (t >= E) return;
    int d = ei[E + t];
    ssrc[rowptr[d] + slot[t]] = ei[t];
}

// ---------------- layer1 aggregate + ELU + GEMM2 + att2 ----------------
__global__ __launch_bounds__(256) void agg1_k(
    const int* __restrict__ rowptr, const int* __restrict__ ssrc,
    const float* __restrict__ asrc1, const float* __restrict__ adst1,
    const ushort* __restrict__ h1b, const float* __restrict__ b1,
    const float* __restrict__ W2, const float* __restrict__ att_src2, const float* __restrict__ att_dst2,
    ushort* __restrict__ h2b, float* __restrict__ asrc2, float* __restrict__ adst2, int n)
{
    __shared__ float Ws2[64 * 17];
    __shared__ float sv[4][64];
    const int t = threadIdx.x;
    #pragma unroll
    for (int k = 0; k < 4; ++k) {
        int idx = t + k * 256;
        Ws2[(idx >> 4) * 17 + (idx & 15)] = W2[idx];
    }
    __syncthreads();

    const int wv = t >> 6;
    const int j  = t & 63;
    const int g  = j >> 3;
    const int h  = j & 7;
    const int node = blockIdx.x * 4 + wv;
    const bool active = node < n;

    if (active) {
        const int d = node;
        const int start = rowptr[d], end = rowptr[d + 1];
        const float adsth = adst1[d * 8 + h];
        float acc0[8] = {}, acc1[8] = {};
        float dsum0 = 0.f, dsum1 = 0.f;
        for (int base = start - 1; base < end; base += 16) {
            int i0 = base + g;
            int i1 = i0 + 8;
            if (i0 < end) {
                int s = (i0 < start) ? d : ssrc[i0];
                float e = asrc1[s * 8 + h] + adsth;
                e = e > 0.f ? e : NEG_SLOPE * e;
                float ex = __expf(e);
                dsum0 += ex;
                u16x8 hv = *(const u16x8*)(h1b + (size_t)s * 64 + h * 8);
                #pragma unroll
                for (int c = 0; c < 8; ++c) acc0[c] += ex * bf2f(hv[c]);
            }
            if (i1 < end) {
                int s = ssrc[i1];
                float e = asrc1[s * 8 + h] + adsth;
                e = e > 0.f ? e : NEG_SLOPE * e;
                float ex = __expf(e);
                dsum1 += ex;
                u16x8 hv = *(const u16x8*)(h1b + (size_t)s * 64 + h * 8);
                #pragma unroll
                for (int c = 0; c < 8; ++c) acc1[c] += ex * bf2f(hv[c]);
            }
        }
        float dsum = dsum0 + dsum1;
        float acc[8];
        #pragma unroll
        for (int c = 0; c < 8; ++c) acc[c] = acc0[c] + acc1[c];
        #pragma unroll
        for (int o = 8; o < 64; o <<= 1) {
            dsum += __shfl_xor(dsum, o);
            #pragma unroll
            for (int c = 0; c < 8; ++c) acc[c] += __shfl_xor(acc[c], o);
        }
        if (g == 0) {
            float den = dsum + 1e-16f;
            #pragma unroll
            for (int c = 0; c < 8; ++c) {
                float v = acc[c] / den + b1[h * 8 + c];
                v = v > 0.f ? v : (__expf(v) - 1.f);   // ELU
                sv[wv][h * 8 + c] = v;
            }
        }
    }
    __syncthreads();

    if (active) {
        const int c = j & 15, q = j >> 4;
        float p = 0.f;
        #pragma unroll
        for (int r = 0; r < 16; ++r)
            p += sv[wv][q * 16 + r] * Ws2[(q * 16 + r) * 17 + c];
        p += __shfl_xor(p, 16);
        p += __shfl_xor(p, 32);
        if (j < 16) h2b[(size_t)node * 16 + j] = f2bf(p);
        float as2 = p * att_src2[c];
        float ad2 = p * att_dst2[c];
        #pragma unroll
        for (int o = 1; o < 16; o <<= 1) { as2 += __shfl_xor(as2, o, 16); ad2 += __shfl_xor(ad2, o, 16); }
        if (j == 0) { asrc2[node] = as2; adst2[node] = ad2; }
    }
}

// ---------------- layer2 aggregate + log_softmax ----------------
__global__ __launch_bounds__(256) void agg2_k(
    const int* __restrict__ rowptr, const int* __restrict__ ssrc,
    const float* __restrict__ asrc2, const float* __restrict__ adst2,
    const ushort* __restrict__ h2b, const float* __restrict__ b2,
    float* __restrict__ out, int n)
{
    const int t = threadIdx.x;
    const int node = blockIdx.x * 4 + (t >> 6);
    if (node >= n) return;
    const int j = t & 63;
    const int g = j >> 2;
    const int q = j & 3;
    const int d = node;
    const int start = rowptr[d], end = rowptr[d + 1];
    const float adst_d = adst2[d];

    float acc0[4] = {}, acc1[4] = {};
    float dsum0 = 0.f, dsum1 = 0.f;
    for (int base = start - 1; base < end; base += 32) {
        int i0 = base + g;
        int i1 = i0 + 16;
        if (i0 < end) {
            int s = (i0 < start) ? d : ssrc[i0];
            float e = asrc2[s] + adst_d;
            e = e > 0.f ? e : NEG_SLOPE * e;
            float ex = __expf(e);
            dsum0 += ex;
            u16x4 hv = *(const u16x4*)(h2b + (size_t)s * 16 + q * 4);
            #pragma unroll
            for (int c = 0; c < 4; ++c) acc0[c] += ex * bf2f(hv[c]);
        }
        if (i1 < end) {
            int s = ssrc[i1];
            float e = asrc2[s] + adst_d;
            e = e > 0.f ? e : NEG_SLOPE * e;
            float ex = __expf(e);
            dsum1 += ex;
            u16x4 hv = *(const u16x4*)(h2b + (size_t)s * 16 + q * 4);
            #pragma unroll
            for (int c = 0; c < 4; ++c) acc1[c] += ex * bf2f(hv[c]);
        }
    }
    float dsum = dsum0 + dsum1;
    float acc[4];
    #pragma unroll
    for (int c = 0; c < 4; ++c) acc[c] = acc0[c] + acc1[c];
    #pragma unroll
    for (int o = 4; o < 64; o <<= 1) {
        dsum += __shfl_xor(dsum, o);
        #pragma unroll
        for (int c = 0; c < 4; ++c) acc[c] += __shfl_xor(acc[c], o);
    }

    const float den = dsum + 1e-16f;
    float v[4];
    float m = -1e30f;
    #pragma unroll
    for (int c = 0; c < 4; ++c) {
        v[c] = acc[c] / den + b2[q * 4 + c];
        m = fmaxf(m, v[c]);
    }
    m = fmaxf(m, __shfl_xor(m, 1));
    m = fmaxf(m, __shfl_xor(m, 2));
    float s2 = 0.f;
    #pragma unroll
    for (int c = 0; c < 4; ++c) s2 += __expf(v[c] - m);
    s2 += __shfl_xor(s2, 1);
    s2 += __shfl_xor(s2, 2);
    const float lse = m + logf(s2);
    if (j < 4) {
        float4 o4 = make_float4(v[0] - lse, v[1] - lse, v[2] - lse, v[3] - lse);
        *(float4*)(out + (size_t)d * 16 + q * 4) = o4;
    }
}

extern "C" void kernel_launch(void* const* d_in, const int* in_sizes, int n_in,
                              void* d_out, int out_size, void* d_ws, size_t ws_size,
                              hipStream_t stream) {
    const float* x        = (const float*)d_in[0];
    const int*   ei       = (const int*)d_in[1];
    const float* W1       = (const float*)d_in[2];
    const float* att_src1 = (const float*)d_in[3];
    const float* att_dst1 = (const float*)d_in[4];
    const float* b1       = (const float*)d_in[5];
    const float* W2       = (const float*)d_in[6];
    const float* att_src2 = (const float*)d_in[7];
    const float* att_dst2 = (const float*)d_in[8];
    const float* b2       = (const float*)d_in[9];
    float* out = (float*)d_out;

    const int n = in_sizes[0] / 512;
    const int E = in_sizes[1] / 2;

    char* base = (char*)d_ws;
    ushort* h1b   = (ushort*)(base);                          // 128n B
    ushort* h2b   = (ushort*)(base + (size_t)128 * n);        // 32n B
    float*  asrc1 = (float*) (base + (size_t)160 * n);        // 32n B
    float*  adst1 = (float*) (base + (size_t)192 * n);        // 32n B
    float*  asrc2 = (float*) (base + (size_t)224 * n);        // 4n B
    float*  adst2 = (float*) (base + (size_t)228 * n);        // 4n B
    int*    rowptr= (int*)   (base + (size_t)232 * n);        // 4n+4 B
    int*    cnt   = (int*)   (base + (size_t)236 * n + 4);    // 4n B
    int*    bsum  = (int*)   (base + (size_t)240 * n + 4);    // 1024 B
    int*    slot  = (int*)   (base + (size_t)240 * n + 4 + 1024); // 4E B
    int*    ssrc  = slot + E;                                 // 4E B

    hipMemsetAsync(cnt, 0, (size_t)4 * n, stream);

    hist_k<<<(E + 255) / 256, 256, 0, stream>>>(ei, cnt, slot, E);
    scan_a<<<SCAN_B, SCAN_T, 0, stream>>>(cnt, bsum, n);
    scan_b<<<SCAN_B, SCAN_T, 0, stream>>>(cnt, bsum, rowptr, n, E);
    scatter_k<<<(E + 255) / 256, 256, 0, stream>>>(ei, rowptr, slot, ssrc, E);

    gemm1_mfma<<<(n + 63) / 64, 256, 0, stream>>>(x, W1, att_src1, att_dst1, h1b, asrc1, adst1, n);

    agg1_k<<<(n + 3) / 4, 256, 0, stream>>>(rowptr, ssrc, asrc1, adst1, h1b, b1,
                                            W2, att_src2, att_dst2, h2b, asrc2, adst2, n);

    agg2_k<<<(n + 3) / 4, 256, 0, stream>>>(rowptr, ssrc, asrc2, adst2, h2b, b2, out, n);
}

// Round 10
// 269.304 us; speedup vs baseline: 13.7615x; 1.1146x over previous
//
#include <hip/hip_runtime.h>
#include <hip/hip_bf16.h>

#define NEG_SLOPE 0.2f

typedef __attribute__((ext_vector_type(8))) short  bf16x8;
typedef __attribute__((ext_vector_type(8))) unsigned short u16x8;
typedef __attribute__((ext_vector_type(4))) unsigned short u16x4;
typedef __attribute__((ext_vector_type(4))) float  f32x4;

static __device__ __forceinline__ ushort f2bf(float f) {
    union { float f; unsigned int u; } c; c.f = f;
    unsigned int r = c.u + 0x7fffu + ((c.u >> 16) & 1u);   // round-to-nearest-even
    return (ushort)(r >> 16);
}
static __device__ __forceinline__ float bf2f(ushort u) {
    union { unsigned int u; float f; } c; c.u = ((unsigned int)u) << 16;
    return c.f;
}

// ---------------- prep: W1T[c][k] = bf16(W1[k][c]), 64x512 ----------------
__global__ __launch_bounds__(256) void prep_w1(const float* __restrict__ W, ushort* __restrict__ W1T)
{
    int idx = blockIdx.x * 256 + threadIdx.x;
    if (idx >= 64 * 512) return;
    int c = idx >> 9, k = idx & 511;
    W1T[idx] = f2bf(W[k * 64 + c]);
}

// ---------------- GEMM1 via bf16 MFMA: 8 waves, clean staging, barrier-free K, fused att1 ----
__global__ __launch_bounds__(512, 4) void gemm1_mfma(
    const float* __restrict__ x, const ushort* __restrict__ W1T,
    const float* __restrict__ att_src, const float* __restrict__ att_dst,
    ushort* __restrict__ h1b, float* __restrict__ asrc, float* __restrict__ adst, int n)
{
    __shared__ ushort Bs[64][520];  // [col][k] bf16, padded row (1040B)
    const int t    = threadIdx.x;
    const int lane = t & 63;
    const int wv   = t >> 6;        // 0..7
    const int rb   = blockIdx.x * 128;
    const int m    = lane & 15;
    const int kg   = lane >> 4;

    // stage W1T -> Bs: 4096 chunks of 8 ushorts (16B); 8 per thread.
    // (R8/R9 bug: used 2048 chunks at 16-ushort stride -> half of each row uninitialized.)
    #pragma unroll
    for (int i = 0; i < 8; ++i) {
        int chunk = t + i * 512;        // 0..4095
        int c  = chunk >> 6;            // 64 chunks of 8 ushorts per row
        int ko = (chunk & 63) * 8;
        *(u16x8*)&Bs[c][ko] = *(const u16x8*)(W1T + c * 512 + ko);
    }

    const int arow  = rb + wv * 16 + m;
    const int arowc = min(arow, n - 1);
    const float* xp = x + (size_t)arowc * 512 + kg * 8;

    f32x4 acc[4] = {};
    __syncthreads();

    // depth-2 register prefetch, no barriers in K-loop
    float4 lo0 = *(const float4*)(xp);
    float4 hi0 = *(const float4*)(xp + 4);
    float4 lo1 = *(const float4*)(xp + 32);
    float4 hi1 = *(const float4*)(xp + 36);
    #pragma unroll
    for (int k32 = 0; k32 < 16; ++k32) {
        float4 nlo = {}, nhi = {};
        if (k32 < 14) {
            nlo = *(const float4*)(xp + (k32 + 2) * 32);
            nhi = *(const float4*)(xp + (k32 + 2) * 32 + 4);
        }
        u16x8 a;
        a[0] = f2bf(lo0.x); a[1] = f2bf(lo0.y); a[2] = f2bf(lo0.z); a[3] = f2bf(lo0.w);
        a[4] = f2bf(hi0.x); a[5] = f2bf(hi0.y); a[6] = f2bf(hi0.z); a[7] = f2bf(hi0.w);
        bf16x8 af = *(bf16x8*)&a;
        #pragma unroll
        for (int t4 = 0; t4 < 4; ++t4) {
            bf16x8 bfr = *(const bf16x8*)&Bs[t4 * 16 + m][k32 * 32 + kg * 8];
            acc[t4] = __builtin_amdgcn_mfma_f32_16x16x32_bf16(af, bfr, acc[t4], 0, 0, 0);
        }
        lo0 = lo1; hi0 = hi1; lo1 = nlo; hi1 = nhi;
    }

    // epilogue: C/D col=m, row=kg*4+i; fused per-head att reductions
    #pragma unroll
    for (int t4 = 0; t4 < 4; ++t4) {
        const float as_w = att_src[t4 * 16 + m];
        const float ad_w = att_dst[t4 * 16 + m];
        #pragma unroll
        for (int i = 0; i < 4; ++i) {
            int gr = rb + wv * 16 + kg * 4 + i;
            float v = acc[t4][i];
            float ps = v * as_w, pd = v * ad_w;
            ps += __shfl_xor(ps, 1); pd += __shfl_xor(pd, 1);
            ps += __shfl_xor(ps, 2); pd += __shfl_xor(pd, 2);
            ps += __shfl_xor(ps, 4); pd += __shfl_xor(pd, 4);
            if (gr < n) {
                h1b[(size_t)gr * 64 + t4 * 16 + m] = f2bf(v);
                if ((m & 7) == 0) {
                    int h = t4 * 2 + (m >> 3);
                    asrc[gr * 8 + h] = ps;
                    adst[gr * 8 + h] = pd;
                }
            }
        }
    }
}

// ---------------- CSR build: histogram also records each edge's slot ----------------
__global__ __launch_bounds__(256) void hist_k(
    const int* __restrict__ ei, int* __restrict__ cnt, int* __restrict__ slot, int E)
{
    int t = blockIdx.x * blockDim.x + threadIdx.x;
    if (t < E) slot[t] = atomicAdd(&cnt[ei[E + t]], 1);
}

#define SCAN_B 256
#define SCAN_T 256

__global__ __launch_bounds__(SCAN_T) void scan_a(const int* __restrict__ cnt, int* __restrict__ bsum, int n)
{
    __shared__ int sh[SCAN_T];
    const int tid = threadIdx.x;
    const int per = (n + SCAN_B * SCAN_T - 1) / (SCAN_B * SCAN_T);
    const int lo = (blockIdx.x * SCAN_T + tid) * per;
    const int hi = min(n, lo + per);
    int s = 0;
    for (int i = lo; i < hi; ++i) s += cnt[i];
    sh[tid] = s;
    __syncthreads();
    #pragma unroll
    for (int o = SCAN_T / 2; o; o >>= 1) {
        if (tid < o) sh[tid] += sh[tid + o];
        __syncthreads();
    }
    if (tid == 0) bsum[blockIdx.x] = sh[0];
}

__global__ __launch_bounds__(SCAN_T) void scan_b(
    const int* __restrict__ cnt, const int* __restrict__ bsum,
    int* __restrict__ rowptr, int n, int E)
{
    __shared__ int sb[SCAN_B];
    __shared__ int sh[SCAN_T];
    const int tid = threadIdx.x;
    sb[tid] = bsum[tid];
    __syncthreads();
    #pragma unroll
    for (int o = 1; o < SCAN_B; o <<= 1) {
        int v = (tid >= o) ? sb[tid - o] : 0;
        __syncthreads();
        sb[tid] += v;
        __syncthreads();
    }
    const int boff = (blockIdx.x == 0) ? 0 : sb[blockIdx.x - 1];

    const int per = (n + SCAN_B * SCAN_T - 1) / (SCAN_B * SCAN_T);
    const int lo = (blockIdx.x * SCAN_T + tid) * per;
    const int hi = min(n, lo + per);
    int s = 0;
    for (int i = lo; i < hi; ++i) s += cnt[i];
    sh[tid] = s;
    __syncthreads();
    #pragma unroll
    for (int o = 1; o < SCAN_T; o <<= 1) {
        int v = (tid >= o) ? sh[tid - o] : 0;
        __syncthreads();
        sh[tid] += v;
        __syncthreads();
    }
    int excl = boff + ((tid == 0) ? 0 : sh[tid - 1]);
    for (int i = lo; i < hi; ++i) { rowptr[i] = excl; excl += cnt[i]; }
    if (blockIdx.x == 0 && tid == 0) rowptr[n] = E;
}

__global__ __launch_bounds__(256) void scatter_k(
    const int* __restrict__ ei, const int* __restrict__ rowptr,
    const int* __restrict__ slot, int* __restrict__ ssrc, int E)
{
    int t = blockIdx.x * blockDim.x + threadIdx.x;
    if (t >= E) return;
    int d = ei[E + t];
    ssrc[rowptr[d] + slot[t]] = ei[t];
}

// ---------------- layer1 aggregate + ELU + GEMM2 + att2 ----------------
__global__ __launch_bounds__(256) void agg1_k(
    const int* __restrict__ rowptr, const int* __restrict__ ssrc,
    const float* __restrict__ asrc1, const float* __restrict__ adst1,
    const ushort* __restrict__ h1b, const float* __restrict__ b1,
    const float* __restrict__ W2, const float* __restrict__ att_src2, const float* __restrict__ att_dst2,
    ushort* __restrict__ h2b, float* __restrict__ asrc2, float* __restrict__ adst2, int n)
{
    __shared__ float Ws2[64 * 17];
    __shared__ float sv[4][64];
    const int t = threadIdx.x;
    #pragma unroll
    for (int k = 0; k < 4; ++k) {
        int idx = t + k * 256;
        Ws2[(idx >> 4) * 17 + (idx & 15)] = W2[idx];
    }
    __syncthreads();

    const int wv = t >> 6;
    const int j  = t & 63;
    const int g  = j >> 3;
    const int h  = j & 7;
    const int node = blockIdx.x * 4 + wv;
    const bool active = node < n;

    if (active) {
        const int d = node;
        const int start = rowptr[d], end = rowptr[d + 1];
        const float adsth = adst1[d * 8 + h];
        float acc0[8] = {}, acc1[8] = {};
        float dsum0 = 0.f, dsum1 = 0.f;
        for (int base = start - 1; base < end; base += 16) {
            int i0 = base + g;
            int i1 = i0 + 8;
            if (i0 < end) {
                int s = (i0 < start) ? d : ssrc[i0];
                float e = asrc1[s * 8 + h] + adsth;
                e = e > 0.f ? e : NEG_SLOPE * e;
                float ex = __expf(e);
                dsum0 += ex;
                u16x8 hv = *(const u16x8*)(h1b + (size_t)s * 64 + h * 8);
                #pragma unroll
                for (int c = 0; c < 8; ++c) acc0[c] += ex * bf2f(hv[c]);
            }
            if (i1 < end) {
                int s = ssrc[i1];
                float e = asrc1[s * 8 + h] + adsth;
                e = e > 0.f ? e : NEG_SLOPE * e;
                float ex = __expf(e);
                dsum1 += ex;
                u16x8 hv = *(const u16x8*)(h1b + (size_t)s * 64 + h * 8);
                #pragma unroll
                for (int c = 0; c < 8; ++c) acc1[c] += ex * bf2f(hv[c]);
            }
        }
        float dsum = dsum0 + dsum1;
        float acc[8];
        #pragma unroll
        for (int c = 0; c < 8; ++c) acc[c] = acc0[c] + acc1[c];
        #pragma unroll
        for (int o = 8; o < 64; o <<= 1) {
            dsum += __shfl_xor(dsum, o);
            #pragma unroll
            for (int c = 0; c < 8; ++c) acc[c] += __shfl_xor(acc[c], o);
        }
        if (g == 0) {
            float den = dsum + 1e-16f;
            #pragma unroll
            for (int c = 0; c < 8; ++c) {
                float v = acc[c] / den + b1[h * 8 + c];
                v = v > 0.f ? v : (__expf(v) - 1.f);   // ELU
                sv[wv][h * 8 + c] = v;
            }
        }
    }
    __syncthreads();

    if (active) {
        const int c = j & 15, q = j >> 4;
        float p = 0.f;
        #pragma unroll
        for (int r = 0; r < 16; ++r)
            p += sv[wv][q * 16 + r] * Ws2[(q * 16 + r) * 17 + c];
        p += __shfl_xor(p, 16);
        p += __shfl_xor(p, 32);
        if (j < 16) h2b[(size_t)node * 16 + j] = f2bf(p);
        float as2 = p * att_src2[c];
        float ad2 = p * att_dst2[c];
        #pragma unroll
        for (int o = 1; o < 16; o <<= 1) { as2 += __shfl_xor(as2, o, 16); ad2 += __shfl_xor(ad2, o, 16); }
        if (j == 0) { asrc2[node] = as2; adst2[node] = ad2; }
    }
}

// ---------------- layer2 aggregate + log_softmax ----------------
__global__ __launch_bounds__(256) void agg2_k(
    const int* __restrict__ rowptr, const int* __restrict__ ssrc,
    const float* __restrict__ asrc2, const float* __restrict__ adst2,
    const ushort* __restrict__ h2b, const float* __restrict__ b2,
    float* __restrict__ out, int n)
{
    const int t = threadIdx.x;
    const int node = blockIdx.x * 4 + (t >> 6);
    if (node >= n) return;
    const int j = t & 63;
    const int g = j >> 2;
    const int q = j & 3;
    const int d = node;
    const int start = rowptr[d], end = rowptr[d + 1];
    const float adst_d = adst2[d];

    float acc0[4] = {}, acc1[4] = {};
    float dsum0 = 0.f, dsum1 = 0.f;
    for (int base = start - 1; base < end; base += 32) {
        int i0 = base + g;
        int i1 = i0 + 16;
        if (i0 < end) {
            int s = (i0 < start) ? d : ssrc[i0];
            float e = asrc2[s] + adst_d;
            e = e > 0.f ? e : NEG_SLOPE * e;
            float ex = __expf(e);
            dsum0 += ex;
            u16x4 hv = *(const u16x4*)(h2b + (size_t)s * 16 + q * 4);
            #pragma unroll
            for (int c = 0; c < 4; ++c) acc0[c] += ex * bf2f(hv[c]);
        }
        if (i1 < end) {
            int s = ssrc[i1];
            float e = asrc2[s] + adst_d;
            e = e > 0.f ? e : NEG_SLOPE * e;
            float ex = __expf(e);
            dsum1 += ex;
            u16x4 hv = *(const u16x4*)(h2b + (size_t)s * 16 + q * 4);
            #pragma unroll
            for (int c = 0; c < 4; ++c) acc1[c] += ex * bf2f(hv[c]);
        }
    }
    float dsum = dsum0 + dsum1;
    float acc[4];
    #pragma unroll
    for (int c = 0; c < 4; ++c) acc[c] = acc0[c] + acc1[c];
    #pragma unroll
    for (int o = 4; o < 64; o <<= 1) {
        dsum += __shfl_xor(dsum, o);
        #pragma unroll
        for (int c = 0; c < 4; ++c) acc[c] += __shfl_xor(acc[c], o);
    }

    const float den = dsum + 1e-16f;
    float v[4];
    float m = -1e30f;
    #pragma unroll
    for (int c = 0; c < 4; ++c) {
        v[c] = acc[c] / den + b2[q * 4 + c];
        m = fmaxf(m, v[c]);
    }
    m = fmaxf(m, __shfl_xor(m, 1));
    m = fmaxf(m, __shfl_xor(m, 2));
    float s2 = 0.f;
    #pragma unroll
    for (int c = 0; c < 4; ++c) s2 += __expf(v[c] - m);
    s2 += __shfl_xor(s2, 1);
    s2 += __shfl_xor(s2, 2);
    const float lse = m + logf(s2);
    if (j < 4) {
        float4 o4 = make_float4(v[0] - lse, v[1] - lse, v[2] - lse, v[3] - lse);
        *(float4*)(out + (size_t)d * 16 + q * 4) = o4;
    }
}

static inline size_t align_up(size_t v, size_t a) { return (v + a - 1) & ~(a - 1); }

extern "C" void kernel_launch(void* const* d_in, const int* in_sizes, int n_in,
                              void* d_out, int out_size, void* d_ws, size_t ws_size,
                              hipStream_t stream) {
    const float* x        = (const float*)d_in[0];
    const int*   ei       = (const int*)d_in[1];
    const float* W1       = (const float*)d_in[2];
    const float* att_src1 = (const float*)d_in[3];
    const float* att_dst1 = (const float*)d_in[4];
    const float* b1       = (const float*)d_in[5];
    const float* W2       = (const float*)d_in[6];
    const float* att_src2 = (const float*)d_in[7];
    const float* att_dst2 = (const float*)d_in[8];
    const float* b2       = (const float*)d_in[9];
    float* out = (float*)d_out;

    const int n = in_sizes[0] / 512;
    const int E = in_sizes[1] / 2;

    // 64B-aligned workspace layout
    char* base = (char*)d_ws;
    size_t off = 0;
    ushort* h1b   = (ushort*)(base + off); off = align_up(off + (size_t)128 * n, 64);
    ushort* h2b   = (ushort*)(base + off); off = align_up(off + (size_t)32 * n, 64);
    float*  asrc1 = (float*) (base + off); off = align_up(off + (size_t)32 * n, 64);
    float*  adst1 = (float*) (base + off); off = align_up(off + (size_t)32 * n, 64);
    float*  asrc2 = (float*) (base + off); off = align_up(off + (size_t)4 * n, 64);
    float*  adst2 = (float*) (base + off); off = align_up(off + (size_t)4 * n, 64);
    ushort* W1T   = (ushort*)(base + off); off = align_up(off + (size_t)65536, 64);
    int*    rowptr= (int*)   (base + off); off = align_up(off + (size_t)4 * (n + 1), 64);
    int*    cnt   = (int*)   (base + off); off = align_up(off + (size_t)4 * n, 64);
    int*    bsum  = (int*)   (base + off); off = align_up(off + (size_t)1024, 64);
    int*    slot  = (int*)   (base + off); off = align_up(off + (size_t)4 * E, 64);
    int*    ssrc  = (int*)   (base + off);

    hipMemsetAsync(cnt, 0, (size_t)4 * n, stream);

    prep_w1<<<128, 256, 0, stream>>>(W1, W1T);

    hist_k<<<(E + 255) / 256, 256, 0, stream>>>(ei, cnt, slot, E);
    scan_a<<<SCAN_B, SCAN_T, 0, stream>>>(cnt, bsum, n);
    scan_b<<<SCAN_B, SCAN_T, 0, stream>>>(cnt, bsum, rowptr, n, E);
    scatter_k<<<(E + 255) / 256, 256, 0, stream>>>(ei, rowptr, slot, ssrc, E);

    gemm1_mfma<<<(n + 127) / 128, 512, 0, stream>>>(x, W1T, att_src1, att_dst1, h1b, asrc1, adst1, n);

    agg1_k<<<(n + 3) / 4, 256, 0, stream>>>(rowptr, ssrc, asrc1, adst1, h1b, b1,
                                            W2, att_src2, att_dst2, h2b, asrc2, adst2, n);

    agg2_k<<<(n + 3) / 4, 256, 0, stream>>>(rowptr, ssrc, asrc2, adst2, h2b, b2, out, n);
}

// Round 11
// 268.511 us; speedup vs baseline: 13.8022x; 1.0030x over previous
//
#include <hip/hip_runtime.h>
#include <hip/hip_bf16.h>

#define NEG_SLOPE 0.2f

typedef __attribute__((ext_vector_type(8))) short  bf16x8;
typedef __attribute__((ext_vector_type(8))) unsigned short u16x8;
typedef __attribute__((ext_vector_type(4))) unsigned short u16x4;
typedef __attribute__((ext_vector_type(4))) float  f32x4;

static __device__ __forceinline__ ushort f2bf(float f) {
    union { float f; unsigned int u; } c; c.f = f;
    unsigned int r = c.u + 0x7fffu + ((c.u >> 16) & 1u);   // round-to-nearest-even
    return (ushort)(r >> 16);
}
static __device__ __forceinline__ float bf2f(ushort u) {
    union { unsigned int u; float f; } c; c.u = ((unsigned int)u) << 16;
    return c.f;
}

// ---------------- phase1: prep_w1 (blocks 0..127) + hist (rest), fused ----------------
__global__ __launch_bounds__(256) void phase1_k(
    const float* __restrict__ W, ushort* __restrict__ W1T,
    const int* __restrict__ ei, int* __restrict__ cnt, int* __restrict__ slot, int E)
{
    if (blockIdx.x < 128) {
        int idx = blockIdx.x * 256 + threadIdx.x;      // 32768 = 64*512 exactly
        int c = idx >> 9, k = idx & 511;
        W1T[idx] = f2bf(W[k * 64 + c]);
    } else {
        int t = (blockIdx.x - 128) * 256 + threadIdx.x;
        if (t < E) slot[t] = atomicAdd(&cnt[ei[E + t]], 1);
    }
}

#define SCAN_B 256
#define SCAN_T 256

__global__ __launch_bounds__(SCAN_T) void scan_a(const int* __restrict__ cnt, int* __restrict__ bsum, int n)
{
    __shared__ int sh[SCAN_T];
    const int tid = threadIdx.x;
    const int per = (n + SCAN_B * SCAN_T - 1) / (SCAN_B * SCAN_T);
    const int lo = (blockIdx.x * SCAN_T + tid) * per;
    const int hi = min(n, lo + per);
    int s = 0;
    for (int i = lo; i < hi; ++i) s += cnt[i];
    sh[tid] = s;
    __syncthreads();
    #pragma unroll
    for (int o = SCAN_T / 2; o; o >>= 1) {
        if (tid < o) sh[tid] += sh[tid + o];
        __syncthreads();
    }
    if (tid == 0) bsum[blockIdx.x] = sh[0];
}

__global__ __launch_bounds__(SCAN_T) void scan_b(
    const int* __restrict__ cnt, const int* __restrict__ bsum,
    int* __restrict__ rowptr, int n, int E)
{
    __shared__ int sb[SCAN_B];
    __shared__ int sh[SCAN_T];
    const int tid = threadIdx.x;
    sb[tid] = bsum[tid];
    __syncthreads();
    #pragma unroll
    for (int o = 1; o < SCAN_B; o <<= 1) {
        int v = (tid >= o) ? sb[tid - o] : 0;
        __syncthreads();
        sb[tid] += v;
        __syncthreads();
    }
    const int boff = (blockIdx.x == 0) ? 0 : sb[blockIdx.x - 1];

    const int per = (n + SCAN_B * SCAN_T - 1) / (SCAN_B * SCAN_T);
    const int lo = (blockIdx.x * SCAN_T + tid) * per;
    const int hi = min(n, lo + per);
    int s = 0;
    for (int i = lo; i < hi; ++i) s += cnt[i];
    sh[tid] = s;
    __syncthreads();
    #pragma unroll
    for (int o = 1; o < SCAN_T; o <<= 1) {
        int v = (tid >= o) ? sh[tid - o] : 0;
        __syncthreads();
        sh[tid] += v;
        __syncthreads();
    }
    int excl = boff + ((tid == 0) ? 0 : sh[tid - 1]);
    for (int i = lo; i < hi; ++i) { rowptr[i] = excl; excl += cnt[i]; }
    if (blockIdx.x == 0 && tid == 0) rowptr[n] = E;
}

// ---------------- phase4: scatter (blocks 0..Gs-1, early) + gemm1 MFMA (rest), fused -----
__global__ __launch_bounds__(512, 4) void phase4_k(
    const int* __restrict__ ei, const int* __restrict__ rowptr,
    const int* __restrict__ slot, int* __restrict__ ssrc, int E, int Gs,
    const float* __restrict__ x, const ushort* __restrict__ W1T,
    const float* __restrict__ att_src, const float* __restrict__ att_dst,
    ushort* __restrict__ h1b, float* __restrict__ asrc, float* __restrict__ adst, int n)
{
    __shared__ ushort Bs[64][520];  // [col][k] bf16, padded row (1040B)

    if ((int)blockIdx.x < Gs) {
        // ---- scatter path (no LDS use; HW still reserves it) ----
        int t = blockIdx.x * 512 + threadIdx.x;
        if (t < E) {
            int d = ei[E + t];
            ssrc[rowptr[d] + slot[t]] = ei[t];
        }
        return;
    }

    // ---- gemm1 path ----
    const int t    = threadIdx.x;
    const int lane = t & 63;
    const int wv   = t >> 6;        // 0..7
    const int rb   = (blockIdx.x - Gs) * 128;
    const int m    = lane & 15;
    const int kg   = lane >> 4;

    // stage W1T -> Bs: 4096 chunks of 8 ushorts (16B); 8 per thread
    #pragma unroll
    for (int i = 0; i < 8; ++i) {
        int chunk = t + i * 512;        // 0..4095
        int c  = chunk >> 6;            // 64 chunks of 8 ushorts per row
        int ko = (chunk & 63) * 8;
        *(u16x8*)&Bs[c][ko] = *(const u16x8*)(W1T + c * 512 + ko);
    }

    const int arow  = rb + wv * 16 + m;
    const int arowc = min(arow, n - 1);
    const float* xp = x + (size_t)arowc * 512 + kg * 8;

    f32x4 acc[4] = {};
    __syncthreads();

    // depth-4 register prefetch, no barriers in K-loop
    float4 plo[4], phi[4];
    #pragma unroll
    for (int i = 0; i < 4; ++i) {
        plo[i] = *(const float4*)(xp + i * 32);
        phi[i] = *(const float4*)(xp + i * 32 + 4);
    }
    #pragma unroll
    for (int k32 = 0; k32 < 16; ++k32) {
        float4 lo = plo[k32 & 3], hi = phi[k32 & 3];
        if (k32 + 4 < 16) {
            plo[k32 & 3] = *(const float4*)(xp + (k32 + 4) * 32);
            phi[k32 & 3] = *(const float4*)(xp + (k32 + 4) * 32 + 4);
        }
        u16x8 a;
        a[0] = f2bf(lo.x); a[1] = f2bf(lo.y); a[2] = f2bf(lo.z); a[3] = f2bf(lo.w);
        a[4] = f2bf(hi.x); a[5] = f2bf(hi.y); a[6] = f2bf(hi.z); a[7] = f2bf(hi.w);
        bf16x8 af = *(bf16x8*)&a;
        #pragma unroll
        for (int t4 = 0; t4 < 4; ++t4) {
            bf16x8 bfr = *(const bf16x8*)&Bs[t4 * 16 + m][k32 * 32 + kg * 8];
            acc[t4] = __builtin_amdgcn_mfma_f32_16x16x32_bf16(af, bfr, acc[t4], 0, 0, 0);
        }
    }

    // epilogue: C/D col=m, row=kg*4+i; fused per-head att reductions
    #pragma unroll
    for (int t4 = 0; t4 < 4; ++t4) {
        const float as_w = att_src[t4 * 16 + m];
        const float ad_w = att_dst[t4 * 16 + m];
        #pragma unroll
        for (int i = 0; i < 4; ++i) {
            int gr = rb + wv * 16 + kg * 4 + i;
            float v = acc[t4][i];
            float ps = v * as_w, pd = v * ad_w;
            ps += __shfl_xor(ps, 1); pd += __shfl_xor(pd, 1);
            ps += __shfl_xor(ps, 2); pd += __shfl_xor(pd, 2);
            ps += __shfl_xor(ps, 4); pd += __shfl_xor(pd, 4);
            if (gr < n) {
                h1b[(size_t)gr * 64 + t4 * 16 + m] = f2bf(v);
                if ((m & 7) == 0) {
                    int h = t4 * 2 + (m >> 3);
                    asrc[gr * 8 + h] = ps;
                    adst[gr * 8 + h] = pd;
                }
            }
        }
    }
}

// ---------------- layer1 aggregate + ELU + GEMM2 + att2 ----------------
__global__ __launch_bounds__(256) void agg1_k(
    const int* __restrict__ rowptr, const int* __restrict__ ssrc,
    const float* __restrict__ asrc1, const float* __restrict__ adst1,
    const ushort* __restrict__ h1b, const float* __restrict__ b1,
    const float* __restrict__ W2, const float* __restrict__ att_src2, const float* __restrict__ att_dst2,
    ushort* __restrict__ h2b, float* __restrict__ asrc2, float* __restrict__ adst2, int n)
{
    __shared__ float Ws2[64 * 17];
    __shared__ float sv[4][64];
    const int t = threadIdx.x;
    #pragma unroll
    for (int k = 0; k < 4; ++k) {
        int idx = t + k * 256;
        Ws2[(idx >> 4) * 17 + (idx & 15)] = W2[idx];
    }
    __syncthreads();

    const int wv = t >> 6;
    const int j  = t & 63;
    const int g  = j >> 3;
    const int h  = j & 7;
    const int node = blockIdx.x * 4 + wv;
    const bool active = node < n;

    if (active) {
        const int d = node;
        const int start = rowptr[d], end = rowptr[d + 1];
        const float adsth = adst1[d * 8 + h];
        float acc0[8] = {}, acc1[8] = {};
        float dsum0 = 0.f, dsum1 = 0.f;
        for (int base = start - 1; base < end; base += 16) {
            int i0 = base + g;
            int i1 = i0 + 8;
            if (i0 < end) {
                int s = (i0 < start) ? d : ssrc[i0];
                float e = asrc1[s * 8 + h] + adsth;
                e = e > 0.f ? e : NEG_SLOPE * e;
                float ex = __expf(e);
                dsum0 += ex;
                u16x8 hv = *(const u16x8*)(h1b + (size_t)s * 64 + h * 8);
                #pragma unroll
                for (int c = 0; c < 8; ++c) acc0[c] += ex * bf2f(hv[c]);
            }
            if (i1 < end) {
                int s = ssrc[i1];
                float e = asrc1[s * 8 + h] + adsth;
                e = e > 0.f ? e : NEG_SLOPE * e;
                float ex = __expf(e);
                dsum1 += ex;
                u16x8 hv = *(const u16x8*)(h1b + (size_t)s * 64 + h * 8);
                #pragma unroll
                for (int c = 0; c < 8; ++c) acc1[c] += ex * bf2f(hv[c]);
            }
        }
        float dsum = dsum0 + dsum1;
        float acc[8];
        #pragma unroll
        for (int c = 0; c < 8; ++c) acc[c] = acc0[c] + acc1[c];
        #pragma unroll
        for (int o = 8; o < 64; o <<= 1) {
            dsum += __shfl_xor(dsum, o);
            #pragma unroll
            for (int c = 0; c < 8; ++c) acc[c] += __shfl_xor(acc[c], o);
        }
        if (g == 0) {
            float den = dsum + 1e-16f;
            #pragma unroll
            for (int c = 0; c < 8; ++c) {
                float v = acc[c] / den + b1[h * 8 + c];
                v = v > 0.f ? v : (__expf(v) - 1.f);   // ELU
                sv[wv][h * 8 + c] = v;
            }
        }
    }
    __syncthreads();

    if (active) {
        const int c = j & 15, q = j >> 4;
        float p = 0.f;
        #pragma unroll
        for (int r = 0; r < 16; ++r)
            p += sv[wv][q * 16 + r] * Ws2[(q * 16 + r) * 17 + c];
        p += __shfl_xor(p, 16);
        p += __shfl_xor(p, 32);
        if (j < 16) h2b[(size_t)node * 16 + j] = f2bf(p);
        float as2 = p * att_src2[c];
        float ad2 = p * att_dst2[c];
        #pragma unroll
        for (int o = 1; o < 16; o <<= 1) { as2 += __shfl_xor(as2, o, 16); ad2 += __shfl_xor(ad2, o, 16); }
        if (j == 0) { asrc2[node] = as2; adst2[node] = ad2; }
    }
}

// ---------------- layer2 aggregate + log_softmax ----------------
__global__ __launch_bounds__(256) void agg2_k(
    const int* __restrict__ rowptr, const int* __restrict__ ssrc,
    const float* __restrict__ asrc2, const float* __restrict__ adst2,
    const ushort* __restrict__ h2b, const float* __restrict__ b2,
    float* __restrict__ out, int n)
{
    const int t = threadIdx.x;
    const int node = blockIdx.x * 4 + (t >> 6);
    if (node >= n) return;
    const int j = t & 63;
    const int g = j >> 2;
    const int q = j & 3;
    const int d = node;
    const int start = rowptr[d], end = rowptr[d + 1];
    const float adst_d = adst2[d];

    float acc0[4] = {}, acc1[4] = {};
    float dsum0 = 0.f, dsum1 = 0.f;
    for (int base = start - 1; base < end; base += 32) {
        int i0 = base + g;
        int i1 = i0 + 16;
        if (i0 < end) {
            int s = (i0 < start) ? d : ssrc[i0];
            float e = asrc2[s] + adst_d;
            e = e > 0.f ? e : NEG_SLOPE * e;
            float ex = __expf(e);
            dsum0 += ex;
            u16x4 hv = *(const u16x4*)(h2b + (size_t)s * 16 + q * 4);
            #pragma unroll
            for (int c = 0; c < 4; ++c) acc0[c] += ex * bf2f(hv[c]);
        }
        if (i1 < end) {
            int s = ssrc[i1];
            float e = asrc2[s] + adst_d;
            e = e > 0.f ? e : NEG_SLOPE * e;
            float ex = __expf(e);
            dsum1 += ex;
            u16x4 hv = *(const u16x4*)(h2b + (size_t)s * 16 + q * 4);
            #pragma unroll
            for (int c = 0; c < 4; ++c) acc1[c] += ex * bf2f(hv[c]);
        }
    }
    float dsum = dsum0 + dsum1;
    float acc[4];
    #pragma unroll
    for (int c = 0; c < 4; ++c) acc[c] = acc0[c] + acc1[c];
    #pragma unroll
    for (int o = 4; o < 64; o <<= 1) {
        dsum += __shfl_xor(dsum, o);
        #pragma unroll
        for (int c = 0; c < 4; ++c) acc[c] += __shfl_xor(acc[c], o);
    }

    const float den = dsum + 1e-16f;
    float v[4];
    float m = -1e30f;
    #pragma unroll
    for (int c = 0; c < 4; ++c) {
        v[c] = acc[c] / den + b2[q * 4 + c];
        m = fmaxf(m, v[c]);
    }
    m = fmaxf(m, __shfl_xor(m, 1));
    m = fmaxf(m, __shfl_xor(m, 2));
    float s2 = 0.f;
    #pragma unroll
    for (int c = 0; c < 4; ++c) s2 += __expf(v[c] - m);
    s2 += __shfl_xor(s2, 1);
    s2 += __shfl_xor(s2, 2);
    const float lse = m + logf(s2);
    if (j < 4) {
        float4 o4 = make_float4(v[0] - lse, v[1] - lse, v[2] - lse, v[3] - lse);
        *(float4*)(out + (size_t)d * 16 + q * 4) = o4;
    }
}

static inline size_t align_up(size_t v, size_t a) { return (v + a - 1) & ~(a - 1); }

extern "C" void kernel_launch(void* const* d_in, const int* in_sizes, int n_in,
                              void* d_out, int out_size, void* d_ws, size_t ws_size,
                              hipStream_t stream) {
    const float* x        = (const float*)d_in[0];
    const int*   ei       = (const int*)d_in[1];
    const float* W1       = (const float*)d_in[2];
    const float* att_src1 = (const float*)d_in[3];
    const float* att_dst1 = (const float*)d_in[4];
    const float* b1       = (const float*)d_in[5];
    const float* W2       = (const float*)d_in[6];
    const float* att_src2 = (const float*)d_in[7];
    const float* att_dst2 = (const float*)d_in[8];
    const float* b2       = (const float*)d_in[9];
    float* out = (float*)d_out;

    const int n = in_sizes[0] / 512;
    const int E = in_sizes[1] / 2;

    // 64B-aligned workspace layout
    char* base = (char*)d_ws;
    size_t off = 0;
    ushort* h1b   = (ushort*)(base + off); off = align_up(off + (size_t)128 * n, 64);
    ushort* h2b   = (ushort*)(base + off); off = align_up(off + (size_t)32 * n, 64);
    float*  asrc1 = (float*) (base + off); off = align_up(off + (size_t)32 * n, 64);
    float*  adst1 = (float*) (base + off); off = align_up(off + (size_t)32 * n, 64);
    float*  asrc2 = (float*) (base + off); off = align_up(off + (size_t)4 * n, 64);
    float*  adst2 = (float*) (base + off); off = align_up(off + (size_t)4 * n, 64);
    ushort* W1T   = (ushort*)(base + off); off = align_up(off + (size_t)65536, 64);
    int*    rowptr= (int*)   (base + off); off = align_up(off + (size_t)4 * (n + 1), 64);
    int*    cnt   = (int*)   (base + off); off = align_up(off + (size_t)4 * n, 64);
    int*    bsum  = (int*)   (base + off); off = align_up(off + (size_t)1024, 64);
    int*    slot  = (int*)   (base + off); off = align_up(off + (size_t)4 * E, 64);
    int*    ssrc  = (int*)   (base + off);

    hipMemsetAsync(cnt, 0, (size_t)4 * n, stream);

    // phase 1: prep_w1 + hist fused
    phase1_k<<<128 + (E + 255) / 256, 256, 0, stream>>>(W1, W1T, ei, cnt, slot, E);

    scan_a<<<SCAN_B, SCAN_T, 0, stream>>>(cnt, bsum, n);
    scan_b<<<SCAN_B, SCAN_T, 0, stream>>>(cnt, bsum, rowptr, n, E);

    // phase 4: scatter (early blocks) + gemm1 (rest) fused
    const int Gs = (E + 511) / 512;
    const int Gg = (n + 127) / 128;
    phase4_k<<<Gs + Gg, 512, 0, stream>>>(ei, rowptr, slot, ssrc, E, Gs,
                                          x, W1T, att_src1, att_dst1, h1b, asrc1, adst1, n);

    agg1_k<<<(n + 3) / 4, 256, 0, stream>>>(rowptr, ssrc, asrc1, adst1, h1b, b1,
                                            W2, att_src2, att_dst2, h2b, asrc2, adst2, n);

    agg2_k<<<(n + 3) / 4, 256, 0, stream>>>(rowptr, ssrc, asrc2, adst2, h2b, b2, out, n);
}